// Round 6
// baseline (651.799 us; speedup 1.0000x reference)
//
#include <hip/hip_runtime.h>
#include <stdint.h>

#define NB 32
#define FC 1024
#define DD 512
#define HH 1024
#define BN_EPS 1e-5f

typedef unsigned short u16;
typedef unsigned int u32;
typedef __attribute__((ext_vector_type(8))) short bf16x8;   // 8 bf16 = 4 VGPRs
typedef __attribute__((ext_vector_type(4))) float f32x4;
typedef __attribute__((ext_vector_type(8))) unsigned short ushort8v;

#define AS1 __attribute__((address_space(1)))
#define AS3 __attribute__((address_space(3)))

__device__ __forceinline__ float b2f(u16 u) {
    union { u32 i; float f; } v;
    v.i = ((u32)u) << 16;
    return v.f;
}
__device__ __forceinline__ u16 f2b(float f) {
    union { float f; u32 i; } v;
    v.f = f;
    const u32 b = v.i;
    return (u16)((b + 0x7FFFu + ((b >> 16) & 1u)) >> 16);
}

// async global->LDS, 16B per lane; lds dest must be wave-uniform base
__device__ __forceinline__ void gld16(const u16* g, u16* l) {
    __builtin_amdgcn_global_load_lds((const AS1 u32*)g, (AS3 u32*)l, 16, 0, 0);
}

// XCD-aware tile swizzle: lin%8 = XCD slab over (m,z); each XCD iterates n
// fastest within its slab -> A-tile reuse lands in one XCD's L2.
__device__ __forceinline__ void swizzle_tiles(int& mt, int& nt, int& zt) {
    const int gx = gridDim.x, gy = gridDim.y, gz = gridDim.z;
    const int mzTot = gy * gz;
    if ((mzTot & 7) != 0) { nt = blockIdx.x; mt = blockIdx.y; zt = blockIdx.z; return; }
    long lin = ((long)blockIdx.z * gy + blockIdx.y) * gx + blockIdx.x;
    const int slab = mzTot >> 3;
    const int xcd = (int)(lin & 7);
    const long idx = lin >> 3;
    nt = (int)(idx % gx);
    const int mz = (int)(idx / gx) + xcd * slab;
    mt = mz % gy;
    zt = mz / gy;
}

// ---------------------------------------------------------------------------
// Dtype detection: flag=1 if x is bf16 pairs, 0 if fp32.
// ---------------------------------------------------------------------------
__global__ __launch_bounds__(256) void detect_dtype(
    const u32* __restrict__ x, int* __restrict__ flag)
{
    __shared__ int cnt[256];
    int c = 0;
    for (int i = threadIdx.x; i < 4096; i += 256) {
        const u32 lo = x[i] & 0xFFFFu;
        const u32 e = (lo >> 7) & 0xFFu;
        if (e >= 0x68u && e <= 0x85u) c++;
    }
    cnt[threadIdx.x] = c;
    __syncthreads();
    for (int s = 128; s > 0; s >>= 1) {
        if (threadIdx.x < (unsigned)s) cnt[threadIdx.x] += cnt[threadIdx.x + s];
        __syncthreads();
    }
    if (threadIdx.x == 0) flag[0] = (cnt[0] > 2048) ? 1 : 0;
}

__global__ __launch_bounds__(256) void zero_partials(float* __restrict__ sp) {
    sp[blockIdx.x * 256 + threadIdx.x] = 0.0f;
}

// fold (sum, sumsq) partials -> (scale, shift)
__global__ __launch_bounds__(256) void fold_bn(
    const float* __restrict__ sp, const u16* __restrict__ gamma,
    const u16* __restrict__ beta, float* __restrict__ ssf, float invCnt)
{
    const int f = blockIdx.x * 256 + threadIdx.x;
    if (f < FC) {
        const float mean = sp[f] * invCnt;
        const float var  = sp[FC + f] * invCnt - mean * mean;
        const float rstd = rsqrtf(var + BN_EPS);
        const float sc   = b2f(gamma[f]) * rstd;
        ssf[f]      = sc;
        ssf[FC + f] = b2f(beta[f]) - mean * sc;
    }
}

__global__ __launch_bounds__(256) void convert_to_bf16(
    const void* __restrict__ src, u16* __restrict__ dst, long n4,
    const int* __restrict__ flag)
{
    const bool isbf = (*flag != 0);
    long i4 = (long)blockIdx.x * blockDim.x + threadIdx.x;
    const long stride = (long)gridDim.x * blockDim.x;
    for (; i4 < n4; i4 += stride) {
        const long i = i4 << 2;
        if (isbf) {
            *(ushort4*)(dst + i) = *(const ushort4*)((const u16*)src + i);
        } else {
            const float4 v = *(const float4*)((const float*)src + i);
            ushort4 o;
            o.x = f2b(v.x); o.y = f2b(v.y); o.z = f2b(v.z); o.w = f2b(v.w);
            *(ushort4*)(dst + i) = o;
        }
    }
}

// all 14 params in one launch
struct ConvArgs { const void* src[14]; long off[14]; long n4[14]; };
__global__ __launch_bounds__(256) void convert_params(
    ConvArgs a, u16* __restrict__ dst, const int* __restrict__ flag)
{
    const bool isbf = (*flag != 0);
    const long stride = (long)gridDim.x * blockDim.x;
    for (int s = 0; s < 14; ++s) {
        const long n4 = a.n4[s];
        u16* d = dst + a.off[s];
        const void* sp = a.src[s];
        for (long i4 = (long)blockIdx.x * blockDim.x + threadIdx.x; i4 < n4;
             i4 += stride) {
            const long i = i4 << 2;
            if (isbf) {
                *(ushort4*)(d + i) = *(const ushort4*)((const u16*)sp + i);
            } else {
                const float4 v = *(const float4*)((const float*)sp + i);
                ushort4 o;
                o.x = f2b(v.x); o.y = f2b(v.y); o.z = f2b(v.z); o.w = f2b(v.w);
                *(ushort4*)(d + i) = o;
            }
        }
    }
}

// ---------------------------------------------------------------------------
// 128x128 MFMA GEMM (NT), BK=32, double-buffered, 256 thr = 4 waves:
//   C[m][n]=sum_k A[m][k]*B[n][k] (+bias, softsign, resid, fused BN stats).
// Per-wave 64x64 = 4x4 frags of 16x16x32; acc 64 regs -> ~120 total -> 4
// waves/SIMD; LDS 32 KiB (2 bufs x [A 8K + B 8K]) -> 4 BLOCKS/CU (128/160K).
// vs R3-R5 (512-thr blocks): 4 independent 4-wave barrier domains per CU
// instead of 2 x 8-wave domains -- attacks the per-K-step barrier convoy.
// One __syncthreads per K-step; stage issued BEFORE reads (m97 pattern).
// sym!=0: blockIdx.x indexes the 36-entry lower-triangle (mt>=nt) tile list
// (perfect load balance; upper tiles filled by mirror_upper).
// LDS swizzle (both-sides, verified R1-R5): granule q ^= (r>>1)&3 on global
// source k-offset (gld16 dest linear) and on ds_read offset.
// ---------------------------------------------------------------------------
template<bool BIAS, bool SOFTSIGN, bool STATS, bool RESID>
__global__ __launch_bounds__(256, 4) void gemm128_nt(
    const u16* __restrict__ A, const u16* __restrict__ B,
    const u16* __restrict__ bias, const u16* __restrict__ resid,
    u16* __restrict__ C, float* __restrict__ sp, int sym,
    int M, int N, int K, int lda, int ldb, int ldc,
    long sA, long sB, long sC)
{
    extern __shared__ char smem[];

    int mt, nt, zt;
    if (sym) {
        static const signed char SM[36] = {0,1,1,2,2,2,3,3,3,3,4,4,4,4,4,
            5,5,5,5,5,5,6,6,6,6,6,6,6,7,7,7,7,7,7,7,7};
        static const signed char SN[36] = {0,0,1,0,1,2,0,1,2,3,0,1,2,3,4,
            0,1,2,3,4,5,0,1,2,3,4,5,6,0,1,2,3,4,5,6,7};
        mt = SM[blockIdx.x]; nt = SN[blockIdx.x]; zt = blockIdx.z;
    } else {
        swizzle_tiles(mt, nt, zt);
    }
    const u16* Ab = A + (long)zt * sA + (long)(mt * 128) * lda;
    const u16* Bb = B + (long)zt * sB + (long)(nt * 128) * ldb;
    C += (long)zt * sC;
    const u16* RP = RESID ? (resid + (long)zt * sC) : nullptr;

    const int tid  = threadIdx.x;
    const int lane = tid & 63;
    const int wv   = tid >> 6;          // 0..3
    const int wrr  = (wv >> 1) * 64;    // wave row offset in tile (0/64)
    const int wc   = (wv & 1) * 64;     // wave col offset in tile (0/64)
    const int lm   = lane & 15;
    const int q    = lane >> 4;         // k-granule 0..3

    // ---- swizzled read byte-offsets (A region [128][32], B region [128][32])
    int aOff[4], bOff[4];
    #pragma unroll
    for (int i = 0; i < 4; ++i) {
        const int r = wrr + i * 16 + lm;
        aOff[i] = r * 64 + ((q ^ ((r >> 1) & 3)) << 4);
    }
    #pragma unroll
    for (int j = 0; j < 4; ++j) {
        const int r = wc + j * 16 + lm;
        bOff[j] = r * 64 + ((q ^ ((r >> 1) & 3)) << 4);
    }

    // ---- staging: 4 gld16/thread (wave wv covers rows wv*32..wv*32+31 of
    // both A and B regions, 2 chunks x 16 rows each). gld16 dest linear;
    // swizzle pre-applied to the GLOBAL k-granule (involution).
    const int rw = lane >> 2, qs = lane & 3;
    const int r0s = wv * 32 + rw;
    const int r1s = wv * 32 + 16 + rw;
    const u16* pA0 = Ab + (long)r0s * lda + ((qs ^ ((r0s >> 1) & 3)) << 3);
    const u16* pA1 = Ab + (long)r1s * lda + ((qs ^ ((r1s >> 1) & 3)) << 3);
    const u16* pB0 = Bb + (long)r0s * ldb + ((qs ^ ((r0s >> 1) & 3)) << 3);
    const u16* pB1 = Bb + (long)r1s * ldb + ((qs ^ ((r1s >> 1) & 3)) << 3);
    const int lds0 = wv * 2048;
    const int lds1 = wv * 2048 + 1024;

#define STAGE(bufOff, kofs) { \
    gld16(pA0 + (kofs), (u16*)(smem + (bufOff) + lds0)); \
    gld16(pA1 + (kofs), (u16*)(smem + (bufOff) + lds1)); \
    gld16(pB0 + (kofs), (u16*)(smem + (bufOff) + 8192 + lds0)); \
    gld16(pB1 + (kofs), (u16*)(smem + (bufOff) + 8192 + lds1)); }

    f32x4 acc[4][4] = {};

    const int NT = K >> 5;             // K-steps of 32

    STAGE(0, 0);
    __syncthreads();                   // tile 0 resident (vmcnt+lgkm drained)

    for (int t = 0; t < NT; ++t) {
        const int bo = (t & 1) * 16384;
        const int bn = ((t + 1) & 1) * 16384;
        if (t + 1 < NT) STAGE(bn, (t + 1) * 32);

        bf16x8 a[4], b[4];
        const char* baseA = smem + bo;
        const char* baseB = smem + bo + 8192;
        #pragma unroll
        for (int i = 0; i < 4; ++i) a[i] = *(const bf16x8*)(baseA + aOff[i]);
        #pragma unroll
        for (int j = 0; j < 4; ++j) b[j] = *(const bf16x8*)(baseB + bOff[j]);

        #pragma unroll
        for (int i = 0; i < 4; ++i)
            #pragma unroll
            for (int j = 0; j < 4; ++j)
                acc[i][j] = __builtin_amdgcn_mfma_f32_16x16x32_bf16(
                    a[i], b[j], acc[i][j], 0, 0, 0);

        __syncthreads();               // reads done + next tile resident
    }

#undef STAGE

    // epilogue: per-wave LDS repack (16x65 fp32 each), optional resid add,
    // optional fused BN stats, coalesced bf16 stores
    float* rep = (float*)smem + wv * (16 * 65);
    const int rr = lane >> 2;
    const int cg = lane & 3;
    const int m0 = mt * 128;
    const int n0 = nt * 128;
    #pragma unroll
    for (int i = 0; i < 4; ++i) {      // row-frag: row = wrr + 16*i
        #pragma unroll
        for (int j = 0; j < 4; ++j) {  // col-frag: col = wc + 16*j
            const int col = 16 * j + lm;
            const float bj = BIAS ? b2f(bias[n0 + wc + col]) : 0.0f;
            #pragma unroll
            for (int r = 0; r < 4; ++r) {
                float v = acc[i][j][r] + bj;
                if (SOFTSIGN) v = v / (1.0f + fabsf(v));
                rep[(q * 4 + r) * 65 + col] = v;
            }
        }
        // intra-wave LDS RAW/WAR: wave-lockstep + per-wave buffer
        const int row = m0 + wrr + 16 * i + rr;
        const float* lr = rep + rr * 65 + cg * 16;
        float4 f0 = *(const float4*)(lr + 0);
        float4 f1 = *(const float4*)(lr + 4);
        float4 f2 = *(const float4*)(lr + 8);
        float4 f3 = *(const float4*)(lr + 12);
        if (RESID) {
            const u16* rp = RP + (long)row * ldc + n0 + wc + cg * 16;
            const ushort8v ra = *(const ushort8v*)rp;
            const ushort8v rb = *(const ushort8v*)(rp + 8);
            f0.x += b2f(ra[0]); f0.y += b2f(ra[1]); f0.z += b2f(ra[2]); f0.w += b2f(ra[3]);
            f1.x += b2f(ra[4]); f1.y += b2f(ra[5]); f1.z += b2f(ra[6]); f1.w += b2f(ra[7]);
            f2.x += b2f(rb[0]); f2.y += b2f(rb[1]); f2.z += b2f(rb[2]); f2.w += b2f(rb[3]);
            f3.x += b2f(rb[4]); f3.y += b2f(rb[5]); f3.z += b2f(rb[6]); f3.w += b2f(rb[7]);
        }
        if (STATS) {
            float s1 = (f0.x + f0.y + f0.z + f0.w) + (f1.x + f1.y + f1.z + f1.w)
                     + (f2.x + f2.y + f2.z + f2.w) + (f3.x + f3.y + f3.z + f3.w);
            float s2 = f0.x*f0.x + f0.y*f0.y + f0.z*f0.z + f0.w*f0.w
                     + f1.x*f1.x + f1.y*f1.y + f1.z*f1.z + f1.w*f1.w
                     + f2.x*f2.x + f2.y*f2.y + f2.z*f2.z + f2.w*f2.w
                     + f3.x*f3.x + f3.y*f3.y + f3.z*f3.z + f3.w*f3.w;
            s1 += __shfl_xor(s1, 1); s1 += __shfl_xor(s1, 2);
            s2 += __shfl_xor(s2, 1); s2 += __shfl_xor(s2, 2);
            if (cg == 0) {
                const int ch = row & (FC - 1);
                atomicAdd(&sp[ch], s1);
                atomicAdd(&sp[FC + ch], s2);
            }
        }
        ushort8v o0, o1;
        o0[0] = f2b(f0.x); o0[1] = f2b(f0.y); o0[2] = f2b(f0.z); o0[3] = f2b(f0.w);
        o0[4] = f2b(f1.x); o0[5] = f2b(f1.y); o0[6] = f2b(f1.z); o0[7] = f2b(f1.w);
        o1[0] = f2b(f2.x); o1[1] = f2b(f2.y); o1[2] = f2b(f2.z); o1[3] = f2b(f2.w);
        o1[4] = f2b(f3.x); o1[5] = f2b(f3.y); o1[6] = f2b(f3.z); o1[7] = f2b(f3.w);
        u16* cp = C + (long)row * ldc + n0 + wc + cg * 16;
        *(ushort8v*)cp = o0;
        *(ushort8v*)(cp + 8) = o1;
    }
}

// ---------------------------------------------------------------------------
// mirror the 28 strictly-above-diagonal 128x128 tiles of symmetric W
// (post-softsign): W[r][c] = W[c][r]. Bit-exact vs computing.
// grid: (16 sub-blocks of 32x32, 28 tiles, batch)
// ---------------------------------------------------------------------------
__global__ __launch_bounds__(256) void mirror_upper(
    u16* __restrict__ W, long sW)
{
    static const signed char MTt[28] = {0,0,0,0,0,0,0, 1,1,1,1,1,1, 2,2,2,2,2,
        3,3,3,3, 4,4,4, 5,5, 6};
    static const signed char NTt[28] = {1,2,3,4,5,6,7, 2,3,4,5,6,7, 3,4,5,6,7,
        4,5,6,7, 5,6,7, 6,7, 7};
    __shared__ u16 t[32][33];
    const int id = blockIdx.y;
    const int mt = MTt[id], nt = NTt[id];
    W += (long)blockIdx.z * sW;
    const int rb = blockIdx.x & 3, cb = blockIdx.x >> 2;
    const int dr0 = mt * 128 + rb * 32;
    const int dc0 = nt * 128 + cb * 32;
    const int lx = threadIdx.x & 31;
    const int ly = threadIdx.x >> 5;
    #pragma unroll
    for (int d = 0; d < 32; d += 8)
        t[ly + d][lx] = W[(long)(dc0 + ly + d) * FC + dr0 + lx];
    __syncthreads();
    #pragma unroll
    for (int d = 0; d < 32; d += 8)
        W[(long)(dr0 + ly + d) * FC + dc0 + lx] = t[lx][ly + d];
}

// ---------------------------------------------------------------------------
// transpose fused with BN apply: writes normalized value in-place (dstI) AND
// transposed (dstT). channel = source row (F dim).
// ---------------------------------------------------------------------------
__global__ __launch_bounds__(256) void transpose_bn_bf16(
    const u16* __restrict__ src, u16* __restrict__ dstT,
    u16* __restrict__ dstI, const float* __restrict__ ssf,
    int R, int Cc, long sS, long sD)
{
    __shared__ u16 t[32][33];
    const int bz = blockIdx.z;
    src  += (long)bz * sS;
    dstI += (long)bz * sS;
    dstT += (long)bz * sD;
    const int c0 = blockIdx.x * 32;
    const int r0 = blockIdx.y * 32;
    const int lx = threadIdx.x & 31;
    const int ly = threadIdx.x >> 5;   // 0..7
    #pragma unroll
    for (int d = 0; d < 32; d += 8) {
        const int r = r0 + ly + d;
        const u16 nv = f2b(fmaf(b2f(src[(long)r * Cc + c0 + lx]),
                                ssf[r], ssf[FC + r]));
        t[ly + d][lx] = nv;
        dstI[(long)r * Cc + c0 + lx] = nv;
    }
    __syncthreads();
    #pragma unroll
    for (int d = 0; d < 32; d += 8)
        dstT[(long)(c0 + ly + d) * R + r0 + lx] = t[lx][ly + d];
}

// dst = src*scale+shift (+ add); optional fused stats of the OUTPUT (fp32,
// pre-rounding): wave covers 256 contiguous elems = one channel at Lc=512.
template<bool ADD, bool STATS>
__global__ __launch_bounds__(256) void bn_apply(
    const u16* __restrict__ src, const void* __restrict__ add,
    const int* __restrict__ addflag,
    const float* __restrict__ ss, void* __restrict__ dst,
    const int* __restrict__ outflag, long total4, int lcShift,
    float* __restrict__ sp)
{
    const bool addf32 = ADD && (addflag != nullptr) && (*addflag == 0);
    const bool outf32 = (outflag != nullptr) && (*outflag == 0);
    long i4 = (long)blockIdx.x * blockDim.x + threadIdx.x;
    const long stride = (long)gridDim.x * blockDim.x;
    for (; i4 < total4; i4 += stride) {
        const long i = i4 << 2;
        const int c = (int)((i >> lcShift) & (FC - 1));
        const float sc = ss[c];
        const float sh = ss[FC + c];
        const ushort4 v = *(const ushort4*)(src + i);
        float o0 = fmaf(b2f(v.x), sc, sh);
        float o1 = fmaf(b2f(v.y), sc, sh);
        float o2 = fmaf(b2f(v.z), sc, sh);
        float o3 = fmaf(b2f(v.w), sc, sh);
        if (ADD) {
            if (addf32) {
                const float4 a = *(const float4*)((const float*)add + i);
                o0 += a.x; o1 += a.y; o2 += a.z; o3 += a.w;
            } else {
                const ushort4 a = *(const ushort4*)((const u16*)add + i);
                o0 += b2f(a.x); o1 += b2f(a.y); o2 += b2f(a.z); o3 += b2f(a.w);
            }
        }
        if (STATS) {
            float s1 = o0 + o1 + o2 + o3;
            float s2 = o0 * o0 + o1 * o1 + o2 * o2 + o3 * o3;
            #pragma unroll
            for (int m = 1; m < 64; m <<= 1) {
                s1 += __shfl_xor(s1, m);
                s2 += __shfl_xor(s2, m);
            }
            if ((threadIdx.x & 63) == 0) {
                atomicAdd(&sp[c], s1);
                atomicAdd(&sp[FC + c], s2);
            }
        }
        if (outf32) {
            float4 o; o.x = o0; o.y = o1; o.z = o2; o.w = o3;
            *(float4*)((float*)dst + i) = o;
        } else {
            ushort4 o;
            o.x = f2b(o0); o.y = f2b(o1); o.z = f2b(o2); o.w = f2b(o3);
            *(ushort4*)((u16*)dst + i) = o;
        }
    }
}

extern "C" void kernel_launch(void* const* d_in, const int* in_sizes, int n_in,
                              void* d_out, int out_size, void* d_ws, size_t ws_size,
                              hipStream_t stream)
{
    const size_t MiB = (size_t)1 << 20;
    const long sFH = (long)FC * HH;        // 1,048,576 elems (2 MiB bf16)
    const long sFF = (long)FC * FC;        // 1,048,576
    const long sFD = (long)FC * DD;        //   524,288 (1 MiB)
    const long PE  = (long)NB * FC * DD;   // 16,777,216 (32 MiB)

    const size_t GLDS = 32768;             // 32 KiB LDS dbuf -> 4 blocks/CU
    static bool s_attr = false;
    if (!s_attr) {
        s_attr = true;
        hipFuncSetAttribute(reinterpret_cast<const void*>(&gemm128_nt<true, false, true, false>),
                            hipFuncAttributeMaxDynamicSharedMemorySize, (int)GLDS);
        hipFuncSetAttribute(reinterpret_cast<const void*>(&gemm128_nt<false, true, false, false>),
                            hipFuncAttributeMaxDynamicSharedMemorySize, (int)GLDS);
        hipFuncSetAttribute(reinterpret_cast<const void*>(&gemm128_nt<false, false, false, false>),
                            hipFuncAttributeMaxDynamicSharedMemorySize, (int)GLDS);
        hipFuncSetAttribute(reinterpret_cast<const void*>(&gemm128_nt<true, false, true, true>),
                            hipFuncAttributeMaxDynamicSharedMemorySize, (int)GLDS);
    }

    // bf16 param packing offsets
    long off[16];
    long cur = 0;
    for (int i = 1; i < 15; ++i) { off[i] = cur; cur += ((long)in_sizes[i] + 7) & ~7L; }
    const size_t paramBytes = (size_t)cur * 2;

    // adaptive correlation chunk: scratch = cb*6 MiB (VT + W + V2)
    int cb = 32;
    while (cb > 1 &&
           64 * MiB + (size_t)cb * 6 * MiB + paramBytes + 65536 > ws_size)
        cb >>= 1;

    // ---- workspace layout ----
    u16* V   = (u16*)d_ws;                          // 64 MiB: v (N,F,H)
    u16* VT  = (u16*)((char*)d_ws + 64 * MiB);      // cb*2 MiB: v^T chunk
    u16* WW  = VT + (long)cb * sFH;                 // cb*2 MiB: w chunk
    u16* V2  = WW + (long)cb * sFF;                 // cb*2 MiB: v2 chunk
    u16* WC  = V2 + (long)cb * sFH;                 // packed bf16 params
    char* tail = (char*)(WC + cur);
    tail = (char*)(((uintptr_t)tail + 255) & ~(uintptr_t)255);
    float* SP0  = (float*)tail;                     // 4 stage partial buffers
    float* SP1  = SP0 + 2 * FC;
    float* SP2  = SP1 + 2 * FC;
    float* SP3  = SP2 + 2 * FC;
    float* SSF  = SP3 + 2 * FC;                     // folded (scale,shift)
    int*   FLAG = (int*)(SSF + 2 * FC);
    // d_out (fp32 out => 64 MiB): lower 32 MiB = VX (v3->s->xr), upper = XB
    u16* VX  = (u16*)d_out;
    u16* XB  = (u16*)d_out + PE;                    // x as bf16
    u16* V4  = V;                                   // v4/t (N,F,D) reuses V
    u16* XRT = V + PE;                              // xr^T reuses V upper half

    const dim3 blk(256);
    const dim3 egrid(4096);

    // 0. detect dtype; zero stats partials; convert params + x to bf16
    detect_dtype<<<1, blk, 0, stream>>>((const u32*)d_in[0], FLAG);
    zero_partials<<<dim3(32), blk, 0, stream>>>(SP0);   // zeros SP0..SP3 (8*FC)
    ConvArgs ca;
    for (int i = 1; i < 15; ++i) {
        ca.src[i - 1] = d_in[i];
        ca.off[i - 1] = off[i];
        ca.n4[i - 1]  = (long)in_sizes[i] / 4;
    }
    convert_params<<<dim3(256), blk, 0, stream>>>(ca, WC, FLAG);
    convert_to_bf16<<<dim3(1024), blk, 0, stream>>>(d_in[0], XB, PE / 4, FLAG);

    const u16* W0c = WC + off[1];
    const u16* b0c = WC + off[2];
    const u16* g0c = WC + off[3];
    const u16* be0c = WC + off[4];
    const u16* W1c = WC + off[5];
    const u16* b1c = WC + off[6];
    const u16* g1c = WC + off[7];
    const u16* be1c = WC + off[8];
    const u16* gfc = WC + off[9];
    const u16* bfc = WC + off[10];
    const u16* Wcc = WC + off[11];
    const u16* bcc = WC + off[12];
    const u16* goc = WC + off[13];
    const u16* boc = WC + off[14];

    // 1. v = x @ W0^T + b0  (BN0 stats fused into epilogue -> SP0)
    gemm128_nt<true, false, true, false><<<dim3(HH / 128, (NB * FC) / 128, 1), blk, GLDS, stream>>>(
        XB, W0c, b0c, nullptr, V, SP0, 0, NB * FC, HH, DD, DD, DD, HH, 0, 0, 0);
    fold_bn<<<dim3(4), blk, 0, stream>>>(SP0, g0c, be0c, SSF, 1.0f / (float)(NB * HH));

    // 2-5 per chunk: vT+BN0-apply; w = softsign(v v^T) [36 lower tiles] +
    // mirror 28 upper; v2 = w @ v (via vT); v3 = v2 @ W1^T + b1 (stats->SP1)
    for (int bz0 = 0; bz0 < NB; bz0 += cb) {
        const int c = (NB - bz0 < cb) ? (NB - bz0) : cb;
        transpose_bn_bf16<<<dim3(HH / 32, FC / 32, c), blk, 0, stream>>>(
            V + bz0 * sFH, VT, V + bz0 * sFH, SSF, FC, HH, sFH, sFH);
        gemm128_nt<false, true, false, false><<<dim3(36, 1, c), blk, GLDS, stream>>>(
            V + bz0 * sFH, V + bz0 * sFH, nullptr, nullptr, WW, nullptr, 1,
            FC, FC, HH, HH, HH, FC, sFH, sFH, sFF);
        mirror_upper<<<dim3(16, 28, c), blk, 0, stream>>>(WW, sFF);
        gemm128_nt<false, false, false, false><<<dim3(HH / 128, FC / 128, c), blk, GLDS, stream>>>(
            WW, VT, nullptr, nullptr, V2, nullptr, 0,
            FC, HH, FC, FC, FC, HH, sFF, sFH, sFH);
        gemm128_nt<true, false, true, false><<<dim3(DD / 128, (c * FC) / 128, 1), blk, GLDS, stream>>>(
            V2, W1c, b1c, nullptr, VX + bz0 * sFD, SP1, 0,
            c * FC, DD, HH, HH, HH, DD, 0, 0, 0);
    }
    fold_bn<<<dim3(4), blk, 0, stream>>>(SP1, g1c, be1c, SSF, 1.0f / (float)(NB * DD));

    // 6. s = BN1(v3) + x   (in place VX; s-stats for BNf fused -> SP2)
    bn_apply<true, true><<<egrid, blk, 0, stream>>>(
        VX, XB, nullptr, SSF, VX, nullptr, PE / 4, 9, SP2);
    fold_bn<<<dim3(4), blk, 0, stream>>>(SP2, gfc, bfc, SSF, 1.0f / (float)(NB * DD));

    // 7. xr = BNf(s) fused into xr^T transpose (in-place VX + XRT)
    transpose_bn_bf16<<<dim3(DD / 32, FC / 32, NB), blk, 0, stream>>>(
        VX, XRT, VX, SSF, FC, DD, sFD, sFD);

    // 8. t = Wc @ xr + bc + xr (resid+bias+BNo-stats fused) -> V4
    gemm128_nt<true, false, true, true><<<dim3(DD / 128, FC / 128, NB), blk, GLDS, stream>>>(
        Wcc, XRT, bcc, VX, V4, SP3, 0, FC, DD, FC, FC, FC, DD, 0, sFD, sFD);
    fold_bn<<<dim3(4), blk, 0, stream>>>(SP3, goc, boc, SSF, 1.0f / (float)(NB * DD));

    // 9. out = BNo(t); out dtype per FLAG
    bn_apply<false, false><<<egrid, blk, 0, stream>>>(
        V4, nullptr, nullptr, SSF, d_out, FLAG, PE / 4, 9, nullptr);
}

// Round 7
// 645.345 us; speedup vs baseline: 1.0100x; 1.0100x over previous
//
#include <hip/hip_runtime.h>
#include <stdint.h>

#define NB 32
#define FC 1024
#define DD 512
#define HH 1024
#define BN_EPS 1e-5f

typedef unsigned short u16;
typedef unsigned int u32;
typedef __attribute__((ext_vector_type(8))) short bf16x8;   // 8 bf16 = 4 VGPRs
typedef __attribute__((ext_vector_type(4))) float f32x4;
typedef __attribute__((ext_vector_type(8))) unsigned short ushort8v;

#define AS1 __attribute__((address_space(1)))
#define AS3 __attribute__((address_space(3)))

__device__ __forceinline__ float b2f(u16 u) {
    union { u32 i; float f; } v;
    v.i = ((u32)u) << 16;
    return v.f;
}
__device__ __forceinline__ u16 f2b(float f) {
    union { float f; u32 i; } v;
    v.f = f;
    const u32 b = v.i;
    return (u16)((b + 0x7FFFu + ((b >> 16) & 1u)) >> 16);
}

// async global->LDS, 16B per lane; lds dest must be wave-uniform base
__device__ __forceinline__ void gld16(const u16* g, u16* l) {
    __builtin_amdgcn_global_load_lds((const AS1 u32*)g, (AS3 u32*)l, 16, 0, 0);
}

// XCD-aware tile swizzle: lin%8 = XCD slab over (m,z); each XCD iterates n
// fastest within its slab -> A-tile reuse lands in one XCD's L2.
__device__ __forceinline__ void swizzle_tiles(int& mt, int& nt, int& zt) {
    const int gx = gridDim.x, gy = gridDim.y, gz = gridDim.z;
    const int mzTot = gy * gz;
    if ((mzTot & 7) != 0) { nt = blockIdx.x; mt = blockIdx.y; zt = blockIdx.z; return; }
    long lin = ((long)blockIdx.z * gy + blockIdx.y) * gx + blockIdx.x;
    const int slab = mzTot >> 3;
    const int xcd = (int)(lin & 7);
    const long idx = lin >> 3;
    nt = (int)(idx % gx);
    const int mz = (int)(idx / gx) + xcd * slab;
    mt = mz % gy;
    zt = mz / gy;
}

// ---------------------------------------------------------------------------
// Dtype detection: flag=1 if x is bf16 pairs, 0 if fp32.
// ---------------------------------------------------------------------------
__global__ __launch_bounds__(256) void detect_dtype(
    const u32* __restrict__ x, int* __restrict__ flag)
{
    __shared__ int cnt[256];
    int c = 0;
    for (int i = threadIdx.x; i < 4096; i += 256) {
        const u32 lo = x[i] & 0xFFFFu;
        const u32 e = (lo >> 7) & 0xFFu;
        if (e >= 0x68u && e <= 0x85u) c++;
    }
    cnt[threadIdx.x] = c;
    __syncthreads();
    for (int s = 128; s > 0; s >>= 1) {
        if (threadIdx.x < (unsigned)s) cnt[threadIdx.x] += cnt[threadIdx.x + s];
        __syncthreads();
    }
    if (threadIdx.x == 0) flag[0] = (cnt[0] > 2048) ? 1 : 0;
}

__global__ __launch_bounds__(256) void zero_partials(float* __restrict__ sp) {
    sp[blockIdx.x * 256 + threadIdx.x] = 0.0f;
}

// fold (sum, sumsq) partials -> (scale, shift)
__global__ __launch_bounds__(256) void fold_bn(
    const float* __restrict__ sp, const u16* __restrict__ gamma,
    const u16* __restrict__ beta, float* __restrict__ ssf, float invCnt)
{
    const int f = blockIdx.x * 256 + threadIdx.x;
    if (f < FC) {
        const float mean = sp[f] * invCnt;
        const float var  = sp[FC + f] * invCnt - mean * mean;
        const float rstd = rsqrtf(var + BN_EPS);
        const float sc   = b2f(gamma[f]) * rstd;
        ssf[f]      = sc;
        ssf[FC + f] = b2f(beta[f]) - mean * sc;
    }
}

__global__ __launch_bounds__(256) void convert_to_bf16(
    const void* __restrict__ src, u16* __restrict__ dst, long n4,
    const int* __restrict__ flag)
{
    const bool isbf = (*flag != 0);
    long i4 = (long)blockIdx.x * blockDim.x + threadIdx.x;
    const long stride = (long)gridDim.x * blockDim.x;
    for (; i4 < n4; i4 += stride) {
        const long i = i4 << 2;
        if (isbf) {
            *(ushort4*)(dst + i) = *(const ushort4*)((const u16*)src + i);
        } else {
            const float4 v = *(const float4*)((const float*)src + i);
            ushort4 o;
            o.x = f2b(v.x); o.y = f2b(v.y); o.z = f2b(v.z); o.w = f2b(v.w);
            *(ushort4*)(dst + i) = o;
        }
    }
}

// all 14 params in one launch
struct ConvArgs { const void* src[14]; long off[14]; long n4[14]; };
__global__ __launch_bounds__(256) void convert_params(
    ConvArgs a, u16* __restrict__ dst, const int* __restrict__ flag)
{
    const bool isbf = (*flag != 0);
    const long stride = (long)gridDim.x * blockDim.x;
    for (int s = 0; s < 14; ++s) {
        const long n4 = a.n4[s];
        u16* d = dst + a.off[s];
        const void* sp = a.src[s];
        for (long i4 = (long)blockIdx.x * blockDim.x + threadIdx.x; i4 < n4;
             i4 += stride) {
            const long i = i4 << 2;
            if (isbf) {
                *(ushort4*)(d + i) = *(const ushort4*)((const u16*)sp + i);
            } else {
                const float4 v = *(const float4*)((const float*)sp + i);
                ushort4 o;
                o.x = f2b(v.x); o.y = f2b(v.y); o.z = f2b(v.z); o.w = f2b(v.w);
                *(ushort4*)(d + i) = o;
            }
        }
    }
}

// ---------------------------------------------------------------------------
// 128x256 MFMA GEMM (NT), BK=32, double-buffered (R4 structure -- best
// measured). C[m][n]=sum_k A[m][k]*B[n][k] (+bias, softsign, resid, stats).
// 512 thr = 8 waves (2M x 4N); per-wave 64x64 = 4x4 frags of 16x16x32.
// LDS 48 KiB (2 bufs x [A 8K + B 16K]) -> 2 blocks/CU. One __syncthreads per
// K-step; stage issued BEFORE reads. STATS: per-channel (sum,sumsq) via
// 4-lane shfl reduce + atomicAdd. RESID: +resid (C strides) pre-stats/store.
// sym!=0: blockIdx.x indexes the 20-entry lower-triangle (mt>=2nt) tile list
// (balanced; 12 upper tiles filled by mirror_upper, bit-exact).
// LDS swizzle (both-sides, verified R1-R6): granule q ^= (r>>1)&3 on global
// source k-offset (gld16 dest linear) and on ds_read offset.
// ---------------------------------------------------------------------------
template<bool BIAS, bool SOFTSIGN, bool STATS, bool RESID>
__global__ __launch_bounds__(512, 4) void gemm128x256_nt(
    const u16* __restrict__ A, const u16* __restrict__ B,
    const u16* __restrict__ bias, const u16* __restrict__ resid,
    u16* __restrict__ C, float* __restrict__ sp, int sym,
    int M, int N, int K, int lda, int ldb, int ldc,
    long sA, long sB, long sC)
{
    extern __shared__ char smem[];

    int mt, nt, zt;
    if (sym) {
        static const signed char SM[20] = {0,1,2,3,4,5,6,7, 2,3,4,5,6,7,
                                           4,5,6,7, 6,7};
        static const signed char SN[20] = {0,0,0,0,0,0,0,0, 1,1,1,1,1,1,
                                           2,2,2,2, 3,3};
        mt = SM[blockIdx.x]; nt = SN[blockIdx.x]; zt = blockIdx.z;
    } else {
        swizzle_tiles(mt, nt, zt);
    }
    const u16* Ab = A + (long)zt * sA + (long)(mt * 128) * lda;
    const u16* Bb = B + (long)zt * sB + (long)(nt * 256) * ldb;
    C += (long)zt * sC;
    const u16* RP = RESID ? (resid + (long)zt * sC) : nullptr;

    const int tid  = threadIdx.x;
    const int lane = tid & 63;
    const int wv   = tid >> 6;          // 0..7
    const int wrr  = (wv >> 2) * 64;    // wave row offset in tile (0/64)
    const int wc   = (wv & 3) * 64;     // wave col offset in tile
    const int lm   = lane & 15;
    const int q    = lane >> 4;         // k-granule 0..3

    // ---- swizzled read byte-offsets (A region [128][32], B region [256][32])
    int aOff[4], bOff[4];
    #pragma unroll
    for (int i = 0; i < 4; ++i) {
        const int r = wrr + i * 16 + lm;
        aOff[i] = r * 64 + ((q ^ ((r >> 1) & 3)) << 4);
    }
    #pragma unroll
    for (int j = 0; j < 4; ++j) {
        const int r = wc + j * 16 + lm;
        bOff[j] = r * 64 + ((q ^ ((r >> 1) & 3)) << 4);
    }

    // ---- staging: 3 gld16/thread; gld16 dest linear, swizzle pre-applied to
    // the GLOBAL k-granule (involution == its own inverse).
    const int rw = lane >> 2, qs = lane & 3;
    const int rA  = wv * 16 + rw;
    const int rB0 = wv * 32 + rw;
    const int rB1 = wv * 32 + 16 + rw;
    const u16* pA  = Ab + (long)rA  * lda + ((qs ^ ((rA  >> 1) & 3)) << 3);
    const u16* pB0 = Bb + (long)rB0 * ldb + ((qs ^ ((rB0 >> 1) & 3)) << 3);
    const u16* pB1 = Bb + (long)rB1 * ldb + ((qs ^ ((rB1 >> 1) & 3)) << 3);
    const int ldsA  = wv * 1024;
    const int ldsB0 = wv * 2048;
    const int ldsB1 = wv * 2048 + 1024;

#define STAGE(bufOff, kofs) { \
    gld16(pA  + (kofs), (u16*)(smem + (bufOff) + ldsA)); \
    gld16(pB0 + (kofs), (u16*)(smem + (bufOff) + 8192 + ldsB0)); \
    gld16(pB1 + (kofs), (u16*)(smem + (bufOff) + 8192 + ldsB1)); }

    f32x4 acc[4][4] = {};

    const int NT = K >> 5;             // K-steps of 32

    STAGE(0, 0);
    __syncthreads();                   // tile 0 resident (vmcnt+lgkm drained)

    for (int t = 0; t < NT; ++t) {
        const int bo = (t & 1) * 24576;
        const int bn = ((t + 1) & 1) * 24576;
        if (t + 1 < NT) STAGE(bn, (t + 1) * 32);

        bf16x8 a[4], b[4];
        const char* baseA = smem + bo;
        const char* baseB = smem + bo + 8192;
        #pragma unroll
        for (int i = 0; i < 4; ++i) a[i] = *(const bf16x8*)(baseA + aOff[i]);
        #pragma unroll
        for (int j = 0; j < 4; ++j) b[j] = *(const bf16x8*)(baseB + bOff[j]);

        #pragma unroll
        for (int i = 0; i < 4; ++i)
            #pragma unroll
            for (int j = 0; j < 4; ++j)
                acc[i][j] = __builtin_amdgcn_mfma_f32_16x16x32_bf16(
                    a[i], b[j], acc[i][j], 0, 0, 0);

        __syncthreads();               // reads done + next tile resident
    }

#undef STAGE

    // epilogue: per-wave LDS repack (16x65 fp32 each), optional resid add,
    // optional fused BN stats, coalesced bf16 stores
    float* rep = (float*)smem + wv * (16 * 65);
    const int rr = lane >> 2;
    const int cg = lane & 3;
    const int m0 = mt * 128;
    const int n0 = nt * 256;
    #pragma unroll
    for (int i = 0; i < 4; ++i) {      // row-frag: row = wrr + 16*i
        #pragma unroll
        for (int j = 0; j < 4; ++j) {  // col-frag: col = wc + 16*j
            const int col = 16 * j + lm;
            const float bj = BIAS ? b2f(bias[n0 + wc + col]) : 0.0f;
            #pragma unroll
            for (int r = 0; r < 4; ++r) {
                float v = acc[i][j][r] + bj;
                if (SOFTSIGN) v = v / (1.0f + fabsf(v));
                rep[(q * 4 + r) * 65 + col] = v;
            }
        }
        // intra-wave LDS RAW/WAR: wave-lockstep + per-wave buffer
        const int row = m0 + wrr + 16 * i + rr;
        const float* lr = rep + rr * 65 + cg * 16;
        float4 f0 = *(const float4*)(lr + 0);
        float4 f1 = *(const float4*)(lr + 4);
        float4 f2 = *(const float4*)(lr + 8);
        float4 f3 = *(const float4*)(lr + 12);
        if (RESID) {
            const u16* rp = RP + (long)row * ldc + n0 + wc + cg * 16;
            const ushort8v ra = *(const ushort8v*)rp;
            const ushort8v rb = *(const ushort8v*)(rp + 8);
            f0.x += b2f(ra[0]); f0.y += b2f(ra[1]); f0.z += b2f(ra[2]); f0.w += b2f(ra[3]);
            f1.x += b2f(ra[4]); f1.y += b2f(ra[5]); f1.z += b2f(ra[6]); f1.w += b2f(ra[7]);
            f2.x += b2f(rb[0]); f2.y += b2f(rb[1]); f2.z += b2f(rb[2]); f2.w += b2f(rb[3]);
            f3.x += b2f(rb[4]); f3.y += b2f(rb[5]); f3.z += b2f(rb[6]); f3.w += b2f(rb[7]);
        }
        if (STATS) {
            float s1 = (f0.x + f0.y + f0.z + f0.w) + (f1.x + f1.y + f1.z + f1.w)
                     + (f2.x + f2.y + f2.z + f2.w) + (f3.x + f3.y + f3.z + f3.w);
            float s2 = f0.x*f0.x + f0.y*f0.y + f0.z*f0.z + f0.w*f0.w
                     + f1.x*f1.x + f1.y*f1.y + f1.z*f1.z + f1.w*f1.w
                     + f2.x*f2.x + f2.y*f2.y + f2.z*f2.z + f2.w*f2.w
                     + f3.x*f3.x + f3.y*f3.y + f3.z*f3.z + f3.w*f3.w;
            s1 += __shfl_xor(s1, 1); s1 += __shfl_xor(s1, 2);
            s2 += __shfl_xor(s2, 1); s2 += __shfl_xor(s2, 2);
            if (cg == 0) {
                const int ch = row & (FC - 1);
                atomicAdd(&sp[ch], s1);
                atomicAdd(&sp[FC + ch], s2);
            }
        }
        ushort8v o0, o1;
        o0[0] = f2b(f0.x); o0[1] = f2b(f0.y); o0[2] = f2b(f0.z); o0[3] = f2b(f0.w);
        o0[4] = f2b(f1.x); o0[5] = f2b(f1.y); o0[6] = f2b(f1.z); o0[7] = f2b(f1.w);
        o1[0] = f2b(f2.x); o1[1] = f2b(f2.y); o1[2] = f2b(f2.z); o1[3] = f2b(f2.w);
        o1[4] = f2b(f3.x); o1[5] = f2b(f3.y); o1[6] = f2b(f3.z); o1[7] = f2b(f3.w);
        u16* cp = C + (long)row * ldc + n0 + wc + cg * 16;
        *(ushort8v*)cp = o0;
        *(ushort8v*)(cp + 8) = o1;
    }
}

// ---------------------------------------------------------------------------
// mirror the 12 strictly-above-diagonal 128x256 tiles of symmetric W
// (post-softsign): W[r][c] = W[c][r]. Bit-exact vs computing (same products,
// same k-order, softsign elementwise). grid: (32 sub 32x32, 12 tiles, batch)
// ---------------------------------------------------------------------------
__global__ __launch_bounds__(256) void mirror_upper(
    u16* __restrict__ W, long sW)
{
    static const signed char MTt[12] = {0,1, 0,1,2,3, 0,1,2,3,4,5};
    static const signed char NTt[12] = {1,1, 2,2,2,2, 3,3,3,3,3,3};
    __shared__ u16 t[32][33];
    const int id = blockIdx.y;
    const int mt = MTt[id], nt = NTt[id];
    W += (long)blockIdx.z * sW;
    const int rb = blockIdx.x & 3, cb = blockIdx.x >> 2;
    const int dr0 = mt * 128 + rb * 32;
    const int dc0 = nt * 256 + cb * 32;
    const int lx = threadIdx.x & 31;
    const int ly = threadIdx.x >> 5;
    #pragma unroll
    for (int d = 0; d < 32; d += 8)
        t[ly + d][lx] = W[(long)(dc0 + ly + d) * FC + dr0 + lx];
    __syncthreads();
    #pragma unroll
    for (int d = 0; d < 32; d += 8)
        W[(long)(dr0 + ly + d) * FC + dc0 + lx] = t[lx][ly + d];
}

// ---------------------------------------------------------------------------
// transpose fused with BN apply: writes normalized value in-place (dstI) AND
// transposed (dstT). channel = source row (F dim). Bit-identical to separate
// bn_apply + transpose (same f2b once, then copy).
// ---------------------------------------------------------------------------
__global__ __launch_bounds__(256) void transpose_bn_bf16(
    const u16* __restrict__ src, u16* __restrict__ dstT,
    u16* __restrict__ dstI, const float* __restrict__ ssf,
    int R, int Cc, long sS, long sD)
{
    __shared__ u16 t[32][33];
    const int bz = blockIdx.z;
    src  += (long)bz * sS;
    dstI += (long)bz * sS;
    dstT += (long)bz * sD;
    const int c0 = blockIdx.x * 32;
    const int r0 = blockIdx.y * 32;
    const int lx = threadIdx.x & 31;
    const int ly = threadIdx.x >> 5;   // 0..7
    #pragma unroll
    for (int d = 0; d < 32; d += 8) {
        const int r = r0 + ly + d;
        const u16 nv = f2b(fmaf(b2f(src[(long)r * Cc + c0 + lx]),
                                ssf[r], ssf[FC + r]));
        t[ly + d][lx] = nv;
        dstI[(long)r * Cc + c0 + lx] = nv;
    }
    __syncthreads();
    #pragma unroll
    for (int d = 0; d < 32; d += 8)
        dstT[(long)(c0 + ly + d) * R + r0 + lx] = t[lx][ly + d];
}

// dst = src*scale+shift (+ add); optional fused stats of the OUTPUT (fp32,
// pre-rounding): wave covers 256 contiguous elems = one channel at Lc=512.
template<bool ADD, bool STATS>
__global__ __launch_bounds__(256) void bn_apply(
    const u16* __restrict__ src, const void* __restrict__ add,
    const int* __restrict__ addflag,
    const float* __restrict__ ss, void* __restrict__ dst,
    const int* __restrict__ outflag, long total4, int lcShift,
    float* __restrict__ sp)
{
    const bool addf32 = ADD && (addflag != nullptr) && (*addflag == 0);
    const bool outf32 = (outflag != nullptr) && (*outflag == 0);
    long i4 = (long)blockIdx.x * blockDim.x + threadIdx.x;
    const long stride = (long)gridDim.x * blockDim.x;
    for (; i4 < total4; i4 += stride) {
        const long i = i4 << 2;
        const int c = (int)((i >> lcShift) & (FC - 1));
        const float sc = ss[c];
        const float sh = ss[FC + c];
        const ushort4 v = *(const ushort4*)(src + i);
        float o0 = fmaf(b2f(v.x), sc, sh);
        float o1 = fmaf(b2f(v.y), sc, sh);
        float o2 = fmaf(b2f(v.z), sc, sh);
        float o3 = fmaf(b2f(v.w), sc, sh);
        if (ADD) {
            if (addf32) {
                const float4 a = *(const float4*)((const float*)add + i);
                o0 += a.x; o1 += a.y; o2 += a.z; o3 += a.w;
            } else {
                const ushort4 a = *(const ushort4*)((const u16*)add + i);
                o0 += b2f(a.x); o1 += b2f(a.y); o2 += b2f(a.z); o3 += b2f(a.w);
            }
        }
        if (STATS) {
            float s1 = o0 + o1 + o2 + o3;
            float s2 = o0 * o0 + o1 * o1 + o2 * o2 + o3 * o3;
            #pragma unroll
            for (int m = 1; m < 64; m <<= 1) {
                s1 += __shfl_xor(s1, m);
                s2 += __shfl_xor(s2, m);
            }
            if ((threadIdx.x & 63) == 0) {
                atomicAdd(&sp[c], s1);
                atomicAdd(&sp[FC + c], s2);
            }
        }
        if (outf32) {
            float4 o; o.x = o0; o.y = o1; o.z = o2; o.w = o3;
            *(float4*)((float*)dst + i) = o;
        } else {
            ushort4 o;
            o.x = f2b(o0); o.y = f2b(o1); o.z = f2b(o2); o.w = f2b(o3);
            *(ushort4*)((u16*)dst + i) = o;
        }
    }
}

extern "C" void kernel_launch(void* const* d_in, const int* in_sizes, int n_in,
                              void* d_out, int out_size, void* d_ws, size_t ws_size,
                              hipStream_t stream)
{
    const size_t MiB = (size_t)1 << 20;
    const long sFH = (long)FC * HH;        // 1,048,576 elems (2 MiB bf16)
    const long sFF = (long)FC * FC;        // 1,048,576
    const long sFD = (long)FC * DD;        //   524,288 (1 MiB)
    const long PE  = (long)NB * FC * DD;   // 16,777,216 (32 MiB)

    const size_t GLDS = 49152;             // 48 KiB dynamic LDS -> 2 blocks/CU
    static bool s_attr = false;
    if (!s_attr) {
        s_attr = true;
        hipFuncSetAttribute(reinterpret_cast<const void*>(&gemm128x256_nt<true, false, true, false>),
                            hipFuncAttributeMaxDynamicSharedMemorySize, (int)GLDS);
        hipFuncSetAttribute(reinterpret_cast<const void*>(&gemm128x256_nt<false, true, false, false>),
                            hipFuncAttributeMaxDynamicSharedMemorySize, (int)GLDS);
        hipFuncSetAttribute(reinterpret_cast<const void*>(&gemm128x256_nt<false, false, false, false>),
                            hipFuncAttributeMaxDynamicSharedMemorySize, (int)GLDS);
        hipFuncSetAttribute(reinterpret_cast<const void*>(&gemm128x256_nt<true, false, true, true>),
                            hipFuncAttributeMaxDynamicSharedMemorySize, (int)GLDS);
    }

    // bf16 param packing offsets
    long off[16];
    long cur = 0;
    for (int i = 1; i < 15; ++i) { off[i] = cur; cur += ((long)in_sizes[i] + 7) & ~7L; }
    const size_t paramBytes = (size_t)cur * 2;

    // adaptive correlation chunk: scratch = cb*6 MiB (VT + W + V2)
    int cb = 32;
    while (cb > 1 &&
           64 * MiB + (size_t)cb * 6 * MiB + paramBytes + 65536 > ws_size)
        cb >>= 1;

    // ---- workspace layout ----
    u16* V   = (u16*)d_ws;                          // 64 MiB: v (N,F,H)
    u16* VT  = (u16*)((char*)d_ws + 64 * MiB);      // cb*2 MiB: v^T chunk
    u16* WW  = VT + (long)cb * sFH;                 // cb*2 MiB: w chunk
    u16* V2  = WW + (long)cb * sFF;                 // cb*2 MiB: v2 chunk
    u16* WC  = V2 + (long)cb * sFH;                 // packed bf16 params
    char* tail = (char*)(WC + cur);
    tail = (char*)(((uintptr_t)tail + 255) & ~(uintptr_t)255);
    float* SP0  = (float*)tail;                     // 4 stage partial buffers
    float* SP1  = SP0 + 2 * FC;
    float* SP2  = SP1 + 2 * FC;
    float* SP3  = SP2 + 2 * FC;
    float* SSF  = SP3 + 2 * FC;                     // folded (scale,shift)
    int*   FLAG = (int*)(SSF + 2 * FC);
    // d_out (fp32 out => 64 MiB): lower 32 MiB = VX (v3->s->xr), upper = XB
    u16* VX  = (u16*)d_out;
    u16* XB  = (u16*)d_out + PE;                    // x as bf16
    u16* V4  = V;                                   // v4/t (N,F,D) reuses V
    u16* XRT = V + PE;                              // xr^T reuses V upper half

    const dim3 blk(256);
    const dim3 blk512(512);
    const dim3 egrid(4096);

    // 0. detect dtype; zero stats partials; convert params + x to bf16
    detect_dtype<<<1, blk, 0, stream>>>((const u32*)d_in[0], FLAG);
    zero_partials<<<dim3(32), blk, 0, stream>>>(SP0);   // zeros SP0..SP3 (8*FC)
    ConvArgs ca;
    for (int i = 1; i < 15; ++i) {
        ca.src[i - 1] = d_in[i];
        ca.off[i - 1] = off[i];
        ca.n4[i - 1]  = (long)in_sizes[i] / 4;
    }
    convert_params<<<dim3(256), blk, 0, stream>>>(ca, WC, FLAG);
    convert_to_bf16<<<dim3(1024), blk, 0, stream>>>(d_in[0], XB, PE / 4, FLAG);

    const u16* W0c = WC + off[1];
    const u16* b0c = WC + off[2];
    const u16* g0c = WC + off[3];
    const u16* be0c = WC + off[4];
    const u16* W1c = WC + off[5];
    const u16* b1c = WC + off[6];
    const u16* g1c = WC + off[7];
    const u16* be1c = WC + off[8];
    const u16* gfc = WC + off[9];
    const u16* bfc = WC + off[10];
    const u16* Wcc = WC + off[11];
    const u16* bcc = WC + off[12];
    const u16* goc = WC + off[13];
    const u16* boc = WC + off[14];

    // 1. v = x @ W0^T + b0  (BN0 stats fused into epilogue -> SP0)
    gemm128x256_nt<true, false, true, false><<<dim3(HH / 256, (NB * FC) / 128, 1), blk512, GLDS, stream>>>(
        XB, W0c, b0c, nullptr, V, SP0, 0, NB * FC, HH, DD, DD, DD, HH, 0, 0, 0);
    fold_bn<<<dim3(4), blk, 0, stream>>>(SP0, g0c, be0c, SSF, 1.0f / (float)(NB * HH));

    // 2-5 per chunk: vT+BN0-apply; w = softsign(v v^T) [20 lower tiles] +
    // mirror 12 upper; v2 = w @ v (via vT); v3 = v2 @ W1^T + b1 (stats->SP1)
    for (int bz0 = 0; bz0 < NB; bz0 += cb) {
        const int c = (NB - bz0 < cb) ? (NB - bz0) : cb;
        transpose_bn_bf16<<<dim3(HH / 32, FC / 32, c), blk, 0, stream>>>(
            V + bz0 * sFH, VT, V + bz0 * sFH, SSF, FC, HH, sFH, sFH);
        gemm128x256_nt<false, true, false, false><<<dim3(20, 1, c), blk512, GLDS, stream>>>(
            V + bz0 * sFH, V + bz0 * sFH, nullptr, nullptr, WW, nullptr, 1,
            FC, FC, HH, HH, HH, FC, sFH, sFH, sFF);
        mirror_upper<<<dim3(32, 12, c), blk, 0, stream>>>(WW, sFF);
        gemm128x256_nt<false, false, false, false><<<dim3(HH / 256, FC / 128, c), blk512, GLDS, stream>>>(
            WW, VT, nullptr, nullptr, V2, nullptr, 0,
            FC, HH, FC, FC, FC, HH, sFF, sFH, sFH);
        gemm128x256_nt<true, false, true, false><<<dim3(DD / 256, (c * FC) / 128, 1), blk512, GLDS, stream>>>(
            V2, W1c, b1c, nullptr, VX + bz0 * sFD, SP1, 0,
            c * FC, DD, HH, HH, HH, DD, 0, 0, 0);
    }
    fold_bn<<<dim3(4), blk, 0, stream>>>(SP1, g1c, be1c, SSF, 1.0f / (float)(NB * DD));

    // 6. s = BN1(v3) + x   (in place VX; s-stats for BNf fused -> SP2)
    bn_apply<true, true><<<egrid, blk, 0, stream>>>(
        VX, XB, nullptr, SSF, VX, nullptr, PE / 4, 9, SP2);
    fold_bn<<<dim3(4), blk, 0, stream>>>(SP2, gfc, bfc, SSF, 1.0f / (float)(NB * DD));

    // 7. xr = BNf(s) fused into xr^T transpose (in-place VX + XRT)
    transpose_bn_bf16<<<dim3(DD / 32, FC / 32, NB), blk, 0, stream>>>(
        VX, XRT, VX, SSF, FC, DD, sFD, sFD);

    // 8. t = Wc @ xr + bc + xr (resid+bias+BNo-stats fused) -> V4
    gemm128x256_nt<true, false, true, true><<<dim3(DD / 256, FC / 128, NB), blk512, GLDS, stream>>>(
        Wcc, XRT, bcc, VX, V4, SP3, 0, FC, DD, FC, FC, FC, DD, 0, sFD, sFD);
    fold_bn<<<dim3(4), blk, 0, stream>>>(SP3, goc, boc, SSF, 1.0f / (float)(NB * DD));

    // 9. out = BNo(t); out dtype per FLAG
    bn_apply<false, false><<<egrid, blk, 0, stream>>>(
        V4, nullptr, nullptr, SSF, d_out, FLAG, PE / 4, 9, nullptr);
}

// Round 8
// 613.068 us; speedup vs baseline: 1.0632x; 1.0526x over previous
//
#include <hip/hip_runtime.h>
#include <stdint.h>

#define NB 32
#define FC 1024
#define DD 512
#define HH 1024
#define BN_EPS 1e-5f

typedef unsigned short u16;
typedef unsigned int u32;
typedef __attribute__((ext_vector_type(8))) short bf16x8;   // 8 bf16 = 4 VGPRs
typedef __attribute__((ext_vector_type(4))) float f32x4;
typedef __attribute__((ext_vector_type(8))) unsigned short ushort8v;

#define AS1 __attribute__((address_space(1)))
#define AS3 __attribute__((address_space(3)))

__device__ __forceinline__ float b2f(u16 u) {
    union { u32 i; float f; } v;
    v.i = ((u32)u) << 16;
    return v.f;
}
__device__ __forceinline__ u16 f2b(float f) {
    union { float f; u32 i; } v;
    v.f = f;
    const u32 b = v.i;
    return (u16)((b + 0x7FFFu + ((b >> 16) & 1u)) >> 16);
}

// async global->LDS, 16B per lane; lds dest must be wave-uniform base
__device__ __forceinline__ void gld16(const u16* g, u16* l) {
    __builtin_amdgcn_global_load_lds((const AS1 u32*)g, (AS3 u32*)l, 16, 0, 0);
}

// XCD-aware tile swizzle: lin%8 = XCD slab over (m,z); each XCD iterates n
// fastest within its slab -> A-tile reuse lands in one XCD's L2.
__device__ __forceinline__ void swizzle_tiles(int& mt, int& nt, int& zt) {
    const int gx = gridDim.x, gy = gridDim.y, gz = gridDim.z;
    const int mzTot = gy * gz;
    if ((mzTot & 7) != 0) { nt = blockIdx.x; mt = blockIdx.y; zt = blockIdx.z; return; }
    long lin = ((long)blockIdx.z * gy + blockIdx.y) * gx + blockIdx.x;
    const int slab = mzTot >> 3;
    const int xcd = (int)(lin & 7);
    const long idx = lin >> 3;
    nt = (int)(idx % gx);
    const int mz = (int)(idx / gx) + xcd * slab;
    mt = mz % gy;
    zt = mz / gy;
}

// ---------------------------------------------------------------------------
// Dtype detection: flag=1 if x is bf16 pairs, 0 if fp32.
// ---------------------------------------------------------------------------
__global__ __launch_bounds__(256) void detect_dtype(
    const u32* __restrict__ x, int* __restrict__ flag)
{
    __shared__ int cnt[256];
    int c = 0;
    for (int i = threadIdx.x; i < 4096; i += 256) {
        const u32 lo = x[i] & 0xFFFFu;
        const u32 e = (lo >> 7) & 0xFFu;
        if (e >= 0x68u && e <= 0x85u) c++;
    }
    cnt[threadIdx.x] = c;
    __syncthreads();
    for (int s = 128; s > 0; s >>= 1) {
        if (threadIdx.x < (unsigned)s) cnt[threadIdx.x] += cnt[threadIdx.x + s];
        __syncthreads();
    }
    if (threadIdx.x == 0) flag[0] = (cnt[0] > 2048) ? 1 : 0;
}

__global__ __launch_bounds__(256) void zero_partials(float* __restrict__ sp) {
    sp[blockIdx.x * 256 + threadIdx.x] = 0.0f;
}

// fold (sum, sumsq) partials -> (scale, shift)
__global__ __launch_bounds__(256) void fold_bn(
    const float* __restrict__ sp, const u16* __restrict__ gamma,
    const u16* __restrict__ beta, float* __restrict__ ssf, float invCnt)
{
    const int f = blockIdx.x * 256 + threadIdx.x;
    if (f < FC) {
        const float mean = sp[f] * invCnt;
        const float var  = sp[FC + f] * invCnt - mean * mean;
        const float rstd = rsqrtf(var + BN_EPS);
        const float sc   = b2f(gamma[f]) * rstd;
        ssf[f]      = sc;
        ssf[FC + f] = b2f(beta[f]) - mean * sc;
    }
}

__global__ __launch_bounds__(256) void convert_to_bf16(
    const void* __restrict__ src, u16* __restrict__ dst, long n4,
    const int* __restrict__ flag)
{
    const bool isbf = (*flag != 0);
    long i4 = (long)blockIdx.x * blockDim.x + threadIdx.x;
    const long stride = (long)gridDim.x * blockDim.x;
    for (; i4 < n4; i4 += stride) {
        const long i = i4 << 2;
        if (isbf) {
            *(ushort4*)(dst + i) = *(const ushort4*)((const u16*)src + i);
        } else {
            const float4 v = *(const float4*)((const float*)src + i);
            ushort4 o;
            o.x = f2b(v.x); o.y = f2b(v.y); o.z = f2b(v.z); o.w = f2b(v.w);
            *(ushort4*)(dst + i) = o;
        }
    }
}

// all 14 params in one launch
struct ConvArgs { const void* src[14]; long off[14]; long n4[14]; };
__global__ __launch_bounds__(256) void convert_params(
    ConvArgs a, u16* __restrict__ dst, const int* __restrict__ flag)
{
    const bool isbf = (*flag != 0);
    const long stride = (long)gridDim.x * blockDim.x;
    for (int s = 0; s < 14; ++s) {
        const long n4 = a.n4[s];
        u16* d = dst + a.off[s];
        const void* sp = a.src[s];
        for (long i4 = (long)blockIdx.x * blockDim.x + threadIdx.x; i4 < n4;
             i4 += stride) {
            const long i = i4 << 2;
            if (isbf) {
                *(ushort4*)(d + i) = *(const ushort4*)((const u16*)sp + i);
            } else {
                const float4 v = *(const float4*)((const float*)sp + i);
                ushort4 o;
                o.x = f2b(v.x); o.y = f2b(v.y); o.z = f2b(v.z); o.w = f2b(v.w);
                *(ushort4*)(d + i) = o;
            }
        }
    }
}

// ---------------------------------------------------------------------------
// 128x256 MFMA GEMM (NT), BK=32, double-buffered (R4 structure -- best
// measured over 7 rounds). C[m][n]=sum_k A[m][k]*B[n][k]
//   (+bias, softsign, resid, fused BN stats).
// 512 thr = 8 waves (2M x 4N); per-wave 64x64 = 4x4 frags of 16x16x32.
// LDS 48 KiB (2 bufs x [A 8K + B 16K]) -> 2 blocks/CU. One __syncthreads per
// K-step; stage issued BEFORE reads. STATS: per-channel (sum,sumsq) via
// 4-lane shfl reduce + atomicAdd. RESID: +resid (C strides) pre-stats/store.
// All grids are multiples of 512 blocks (2 blocks/CU x 256 CU) -> no partial
// scheduling rounds (R7 lesson: sym tile-skip at 640 blocks saved 0 wall
// clock -- partial fill costs a whole block-time).
// LDS swizzle (both-sides, verified R1-R7): granule q ^= (r>>1)&3 on global
// source k-offset (gld16 dest linear) and on ds_read offset. Residual
// SQ_LDS_BANK_CONFLICT == 1 cyc per ds_read_b128 (2-way, ~free per m136).
// ---------------------------------------------------------------------------
template<bool BIAS, bool SOFTSIGN, bool STATS, bool RESID>
__global__ __launch_bounds__(512, 4) void gemm128x256_nt(
    const u16* __restrict__ A, const u16* __restrict__ B,
    const u16* __restrict__ bias, const u16* __restrict__ resid,
    u16* __restrict__ C, float* __restrict__ sp,
    int M, int N, int K, int lda, int ldb, int ldc,
    long sA, long sB, long sC)
{
    extern __shared__ char smem[];

    int mt, nt, zt;
    swizzle_tiles(mt, nt, zt);
    const u16* Ab = A + (long)zt * sA + (long)(mt * 128) * lda;
    const u16* Bb = B + (long)zt * sB + (long)(nt * 256) * ldb;
    C += (long)zt * sC;
    const u16* RP = RESID ? (resid + (long)zt * sC) : nullptr;

    const int tid  = threadIdx.x;
    const int lane = tid & 63;
    const int wv   = tid >> 6;          // 0..7
    const int wrr  = (wv >> 2) * 64;    // wave row offset in tile (0/64)
    const int wc   = (wv & 3) * 64;     // wave col offset in tile
    const int lm   = lane & 15;
    const int q    = lane >> 4;         // k-granule 0..3

    // ---- swizzled read byte-offsets (A region [128][32], B region [256][32])
    int aOff[4], bOff[4];
    #pragma unroll
    for (int i = 0; i < 4; ++i) {
        const int r = wrr + i * 16 + lm;
        aOff[i] = r * 64 + ((q ^ ((r >> 1) & 3)) << 4);
    }
    #pragma unroll
    for (int j = 0; j < 4; ++j) {
        const int r = wc + j * 16 + lm;
        bOff[j] = r * 64 + ((q ^ ((r >> 1) & 3)) << 4);
    }

    // ---- staging: 3 gld16/thread; gld16 dest linear, swizzle pre-applied to
    // the GLOBAL k-granule (involution == its own inverse).
    const int rw = lane >> 2, qs = lane & 3;
    const int rA  = wv * 16 + rw;
    const int rB0 = wv * 32 + rw;
    const int rB1 = wv * 32 + 16 + rw;
    const u16* pA  = Ab + (long)rA  * lda + ((qs ^ ((rA  >> 1) & 3)) << 3);
    const u16* pB0 = Bb + (long)rB0 * ldb + ((qs ^ ((rB0 >> 1) & 3)) << 3);
    const u16* pB1 = Bb + (long)rB1 * ldb + ((qs ^ ((rB1 >> 1) & 3)) << 3);
    const int ldsA  = wv * 1024;
    const int ldsB0 = wv * 2048;
    const int ldsB1 = wv * 2048 + 1024;

#define STAGE(bufOff, kofs) { \
    gld16(pA  + (kofs), (u16*)(smem + (bufOff) + ldsA)); \
    gld16(pB0 + (kofs), (u16*)(smem + (bufOff) + 8192 + ldsB0)); \
    gld16(pB1 + (kofs), (u16*)(smem + (bufOff) + 8192 + ldsB1)); }

    f32x4 acc[4][4] = {};

    const int NT = K >> 5;             // K-steps of 32

    STAGE(0, 0);
    __syncthreads();                   // tile 0 resident (vmcnt+lgkm drained)

    for (int t = 0; t < NT; ++t) {
        const int bo = (t & 1) * 24576;
        const int bn = ((t + 1) & 1) * 24576;
        if (t + 1 < NT) STAGE(bn, (t + 1) * 32);

        bf16x8 a[4], b[4];
        const char* baseA = smem + bo;
        const char* baseB = smem + bo + 8192;
        #pragma unroll
        for (int i = 0; i < 4; ++i) a[i] = *(const bf16x8*)(baseA + aOff[i]);
        #pragma unroll
        for (int j = 0; j < 4; ++j) b[j] = *(const bf16x8*)(baseB + bOff[j]);

        #pragma unroll
        for (int i = 0; i < 4; ++i)
            #pragma unroll
            for (int j = 0; j < 4; ++j)
                acc[i][j] = __builtin_amdgcn_mfma_f32_16x16x32_bf16(
                    a[i], b[j], acc[i][j], 0, 0, 0);

        __syncthreads();               // reads done + next tile resident
    }

#undef STAGE

    // epilogue: per-wave LDS repack (16x65 fp32 each), optional resid add,
    // optional fused BN stats, coalesced bf16 stores
    float* rep = (float*)smem + wv * (16 * 65);
    const int rr = lane >> 2;
    const int cg = lane & 3;
    const int m0 = mt * 128;
    const int n0 = nt * 256;
    #pragma unroll
    for (int i = 0; i < 4; ++i) {      // row-frag: row = wrr + 16*i
        #pragma unroll
        for (int j = 0; j < 4; ++j) {  // col-frag: col = wc + 16*j
            const int col = 16 * j + lm;
            const float bj = BIAS ? b2f(bias[n0 + wc + col]) : 0.0f;
            #pragma unroll
            for (int r = 0; r < 4; ++r) {
                float v = acc[i][j][r] + bj;
                if (SOFTSIGN) v = v / (1.0f + fabsf(v));
                rep[(q * 4 + r) * 65 + col] = v;
            }
        }
        // intra-wave LDS RAW/WAR: wave-lockstep + per-wave buffer
        const int row = m0 + wrr + 16 * i + rr;
        const float* lr = rep + rr * 65 + cg * 16;
        float4 f0 = *(const float4*)(lr + 0);
        float4 f1 = *(const float4*)(lr + 4);
        float4 f2 = *(const float4*)(lr + 8);
        float4 f3 = *(const float4*)(lr + 12);
        if (RESID) {
            const u16* rp = RP + (long)row * ldc + n0 + wc + cg * 16;
            const ushort8v ra = *(const ushort8v*)rp;
            const ushort8v rb = *(const ushort8v*)(rp + 8);
            f0.x += b2f(ra[0]); f0.y += b2f(ra[1]); f0.z += b2f(ra[2]); f0.w += b2f(ra[3]);
            f1.x += b2f(ra[4]); f1.y += b2f(ra[5]); f1.z += b2f(ra[6]); f1.w += b2f(ra[7]);
            f2.x += b2f(rb[0]); f2.y += b2f(rb[1]); f2.z += b2f(rb[2]); f2.w += b2f(rb[3]);
            f3.x += b2f(rb[4]); f3.y += b2f(rb[5]); f3.z += b2f(rb[6]); f3.w += b2f(rb[7]);
        }
        if (STATS) {
            float s1 = (f0.x + f0.y + f0.z + f0.w) + (f1.x + f1.y + f1.z + f1.w)
                     + (f2.x + f2.y + f2.z + f2.w) + (f3.x + f3.y + f3.z + f3.w);
            float s2 = f0.x*f0.x + f0.y*f0.y + f0.z*f0.z + f0.w*f0.w
                     + f1.x*f1.x + f1.y*f1.y + f1.z*f1.z + f1.w*f1.w
                     + f2.x*f2.x + f2.y*f2.y + f2.z*f2.z + f2.w*f2.w
                     + f3.x*f3.x + f3.y*f3.y + f3.z*f3.z + f3.w*f3.w;
            s1 += __shfl_xor(s1, 1); s1 += __shfl_xor(s1, 2);
            s2 += __shfl_xor(s2, 1); s2 += __shfl_xor(s2, 2);
            if (cg == 0) {
                const int ch = row & (FC - 1);
                atomicAdd(&sp[ch], s1);
                atomicAdd(&sp[FC + ch], s2);
            }
        }
        ushort8v o0, o1;
        o0[0] = f2b(f0.x); o0[1] = f2b(f0.y); o0[2] = f2b(f0.z); o0[3] = f2b(f0.w);
        o0[4] = f2b(f1.x); o0[5] = f2b(f1.y); o0[6] = f2b(f1.z); o0[7] = f2b(f1.w);
        o1[0] = f2b(f2.x); o1[1] = f2b(f2.y); o1[2] = f2b(f2.z); o1[3] = f2b(f2.w);
        o1[4] = f2b(f3.x); o1[5] = f2b(f3.y); o1[6] = f2b(f3.z); o1[7] = f2b(f3.w);
        u16* cp = C + (long)row * ldc + n0 + wc + cg * 16;
        *(ushort8v*)cp = o0;
        *(ushort8v*)(cp + 8) = o1;
    }
}

// ---------------------------------------------------------------------------
// transpose fused with BN apply: writes normalized value in-place (dstI) AND
// transposed (dstT). channel = source row (F dim). Bit-identical to separate
// bn_apply + transpose (same f2b once, then copy). Verified R5-R7.
// ---------------------------------------------------------------------------
__global__ __launch_bounds__(256) void transpose_bn_bf16(
    const u16* __restrict__ src, u16* __restrict__ dstT,
    u16* __restrict__ dstI, const float* __restrict__ ssf,
    int R, int Cc, long sS, long sD)
{
    __shared__ u16 t[32][33];
    const int bz = blockIdx.z;
    src  += (long)bz * sS;
    dstI += (long)bz * sS;
    dstT += (long)bz * sD;
    const int c0 = blockIdx.x * 32;
    const int r0 = blockIdx.y * 32;
    const int lx = threadIdx.x & 31;
    const int ly = threadIdx.x >> 5;   // 0..7
    #pragma unroll
    for (int d = 0; d < 32; d += 8) {
        const int r = r0 + ly + d;
        const u16 nv = f2b(fmaf(b2f(src[(long)r * Cc + c0 + lx]),
                                ssf[r], ssf[FC + r]));
        t[ly + d][lx] = nv;
        dstI[(long)r * Cc + c0 + lx] = nv;
    }
    __syncthreads();
    #pragma unroll
    for (int d = 0; d < 32; d += 8)
        dstT[(long)(c0 + ly + d) * R + r0 + lx] = t[lx][ly + d];
}

// dst = src*scale+shift (+ add); optional fused stats of the OUTPUT (fp32,
// pre-rounding): wave covers 256 contiguous elems = one channel at Lc=512.
template<bool ADD, bool STATS>
__global__ __launch_bounds__(256) void bn_apply(
    const u16* __restrict__ src, const void* __restrict__ add,
    const int* __restrict__ addflag,
    const float* __restrict__ ss, void* __restrict__ dst,
    const int* __restrict__ outflag, long total4, int lcShift,
    float* __restrict__ sp)
{
    const bool addf32 = ADD && (addflag != nullptr) && (*addflag == 0);
    const bool outf32 = (outflag != nullptr) && (*outflag == 0);
    long i4 = (long)blockIdx.x * blockDim.x + threadIdx.x;
    const long stride = (long)gridDim.x * blockDim.x;
    for (; i4 < total4; i4 += stride) {
        const long i = i4 << 2;
        const int c = (int)((i >> lcShift) & (FC - 1));
        const float sc = ss[c];
        const float sh = ss[FC + c];
        const ushort4 v = *(const ushort4*)(src + i);
        float o0 = fmaf(b2f(v.x), sc, sh);
        float o1 = fmaf(b2f(v.y), sc, sh);
        float o2 = fmaf(b2f(v.z), sc, sh);
        float o3 = fmaf(b2f(v.w), sc, sh);
        if (ADD) {
            if (addf32) {
                const float4 a = *(const float4*)((const float*)add + i);
                o0 += a.x; o1 += a.y; o2 += a.z; o3 += a.w;
            } else {
                const ushort4 a = *(const ushort4*)((const u16*)add + i);
                o0 += b2f(a.x); o1 += b2f(a.y); o2 += b2f(a.z); o3 += b2f(a.w);
            }
        }
        if (STATS) {
            float s1 = o0 + o1 + o2 + o3;
            float s2 = o0 * o0 + o1 * o1 + o2 * o2 + o3 * o3;
            #pragma unroll
            for (int m = 1; m < 64; m <<= 1) {
                s1 += __shfl_xor(s1, m);
                s2 += __shfl_xor(s2, m);
            }
            if ((threadIdx.x & 63) == 0) {
                atomicAdd(&sp[c], s1);
                atomicAdd(&sp[FC + c], s2);
            }
        }
        if (outf32) {
            float4 o; o.x = o0; o.y = o1; o.z = o2; o.w = o3;
            *(float4*)((float*)dst + i) = o;
        } else {
            ushort4 o;
            o.x = f2b(o0); o.y = f2b(o1); o.z = f2b(o2); o.w = f2b(o3);
            *(ushort4*)((u16*)dst + i) = o;
        }
    }
}

extern "C" void kernel_launch(void* const* d_in, const int* in_sizes, int n_in,
                              void* d_out, int out_size, void* d_ws, size_t ws_size,
                              hipStream_t stream)
{
    const size_t MiB = (size_t)1 << 20;
    const long sFH = (long)FC * HH;        // 1,048,576 elems (2 MiB bf16)
    const long sFF = (long)FC * FC;        // 1,048,576
    const long sFD = (long)FC * DD;        //   524,288 (1 MiB)
    const long PE  = (long)NB * FC * DD;   // 16,777,216 (32 MiB)

    const size_t GLDS = 49152;             // 48 KiB dynamic LDS -> 2 blocks/CU
    static bool s_attr = false;
    if (!s_attr) {
        s_attr = true;
        hipFuncSetAttribute(reinterpret_cast<const void*>(&gemm128x256_nt<true, false, true, false>),
                            hipFuncAttributeMaxDynamicSharedMemorySize, (int)GLDS);
        hipFuncSetAttribute(reinterpret_cast<const void*>(&gemm128x256_nt<false, true, false, false>),
                            hipFuncAttributeMaxDynamicSharedMemorySize, (int)GLDS);
        hipFuncSetAttribute(reinterpret_cast<const void*>(&gemm128x256_nt<false, false, false, false>),
                            hipFuncAttributeMaxDynamicSharedMemorySize, (int)GLDS);
        hipFuncSetAttribute(reinterpret_cast<const void*>(&gemm128x256_nt<true, false, true, true>),
                            hipFuncAttributeMaxDynamicSharedMemorySize, (int)GLDS);
    }

    // bf16 param packing offsets
    long off[16];
    long cur = 0;
    for (int i = 1; i < 15; ++i) { off[i] = cur; cur += ((long)in_sizes[i] + 7) & ~7L; }
    const size_t paramBytes = (size_t)cur * 2;

    // adaptive correlation chunk: scratch = cb*6 MiB (VT + W + V2)
    int cb = 32;
    while (cb > 1 &&
           64 * MiB + (size_t)cb * 6 * MiB + paramBytes + 65536 > ws_size)
        cb >>= 1;

    // ---- workspace layout ----
    u16* V   = (u16*)d_ws;                          // 64 MiB: v (N,F,H)
    u16* VT  = (u16*)((char*)d_ws + 64 * MiB);      // cb*2 MiB: v^T chunk
    u16* WW  = VT + (long)cb * sFH;                 // cb*2 MiB: w chunk
    u16* V2  = WW + (long)cb * sFF;                 // cb*2 MiB: v2 chunk
    u16* WC  = V2 + (long)cb * sFH;                 // packed bf16 params
    char* tail = (char*)(WC + cur);
    tail = (char*)(((uintptr_t)tail + 255) & ~(uintptr_t)255);
    float* SP0  = (float*)tail;                     // 4 stage partial buffers
    float* SP1  = SP0 + 2 * FC;
    float* SP2  = SP1 + 2 * FC;
    float* SP3  = SP2 + 2 * FC;
    float* SSF  = SP3 + 2 * FC;                     // folded (scale,shift)
    int*   FLAG = (int*)(SSF + 2 * FC);
    // d_out (fp32 out => 64 MiB): lower 32 MiB = VX (v3->s->xr), upper = XB
    u16* VX  = (u16*)d_out;
    u16* XB  = (u16*)d_out + PE;                    // x as bf16
    u16* V4  = V;                                   // v4/t (N,F,D) reuses V
    u16* XRT = V + PE;                              // xr^T reuses V upper half

    const dim3 blk(256);
    const dim3 blk512(512);
    const dim3 egrid(4096);

    // 0. detect dtype; zero stats partials; convert params + x to bf16
    detect_dtype<<<1, blk, 0, stream>>>((const u32*)d_in[0], FLAG);
    zero_partials<<<dim3(32), blk, 0, stream>>>(SP0);   // zeros SP0..SP3 (8*FC)
    ConvArgs ca;
    for (int i = 1; i < 15; ++i) {
        ca.src[i - 1] = d_in[i];
        ca.off[i - 1] = off[i];
        ca.n4[i - 1]  = (long)in_sizes[i] / 4;
    }
    convert_params<<<dim3(256), blk, 0, stream>>>(ca, WC, FLAG);
    convert_to_bf16<<<dim3(1024), blk, 0, stream>>>(d_in[0], XB, PE / 4, FLAG);

    const u16* W0c = WC + off[1];
    const u16* b0c = WC + off[2];
    const u16* g0c = WC + off[3];
    const u16* be0c = WC + off[4];
    const u16* W1c = WC + off[5];
    const u16* b1c = WC + off[6];
    const u16* g1c = WC + off[7];
    const u16* be1c = WC + off[8];
    const u16* gfc = WC + off[9];
    const u16* bfc = WC + off[10];
    const u16* Wcc = WC + off[11];
    const u16* bcc = WC + off[12];
    const u16* goc = WC + off[13];
    const u16* boc = WC + off[14];

    // 1. v = x @ W0^T + b0  (BN0 stats fused into epilogue -> SP0)
    gemm128x256_nt<true, false, true, false><<<dim3(HH / 256, (NB * FC) / 128, 1), blk512, GLDS, stream>>>(
        XB, W0c, b0c, nullptr, V, SP0, NB * FC, HH, DD, DD, DD, HH, 0, 0, 0);
    fold_bn<<<dim3(4), blk, 0, stream>>>(SP0, g0c, be0c, SSF, 1.0f / (float)(NB * HH));

    // 2-5 per chunk: vT+BN0-apply (V in place + VT); w = softsign(v v^T);
    // v2 = w @ v (via vT); v3 = v2 @ W1^T + b1 (BN1 stats fused -> SP1)
    for (int bz0 = 0; bz0 < NB; bz0 += cb) {
        const int c = (NB - bz0 < cb) ? (NB - bz0) : cb;
        transpose_bn_bf16<<<dim3(HH / 32, FC / 32, c), blk, 0, stream>>>(
            V + bz0 * sFH, VT, V + bz0 * sFH, SSF, FC, HH, sFH, sFH);
        gemm128x256_nt<false, true, false, false><<<dim3(FC / 256, FC / 128, c), blk512, GLDS, stream>>>(
            V + bz0 * sFH, V + bz0 * sFH, nullptr, nullptr, WW, nullptr,
            FC, FC, HH, HH, HH, FC, sFH, sFH, sFF);
        gemm128x256_nt<false, false, false, false><<<dim3(HH / 256, FC / 128, c), blk512, GLDS, stream>>>(
            WW, VT, nullptr, nullptr, V2, nullptr,
            FC, HH, FC, FC, FC, HH, sFF, sFH, sFH);
        gemm128x256_nt<true, false, true, false><<<dim3(DD / 256, (c * FC) / 128, 1), blk512, GLDS, stream>>>(
            V2, W1c, b1c, nullptr, VX + bz0 * sFD, SP1,
            c * FC, DD, HH, HH, HH, DD, 0, 0, 0);
    }
    fold_bn<<<dim3(4), blk, 0, stream>>>(SP1, g1c, be1c, SSF, 1.0f / (float)(NB * DD));

    // 6. s = BN1(v3) + x   (in place VX; s-stats for BNf fused -> SP2)
    bn_apply<true, true><<<egrid, blk, 0, stream>>>(
        VX, XB, nullptr, SSF, VX, nullptr, PE / 4, 9, SP2);
    fold_bn<<<dim3(4), blk, 0, stream>>>(SP2, gfc, bfc, SSF, 1.0f / (float)(NB * DD));

    // 7. xr = BNf(s) fused into xr^T transpose (in-place VX + XRT)
    transpose_bn_bf16<<<dim3(DD / 32, FC / 32, NB), blk, 0, stream>>>(
        VX, XRT, VX, SSF, FC, DD, sFD, sFD);

    // 8. t = Wc @ xr + bc + xr (resid+bias+BNo-stats fused) -> V4
    gemm128x256_nt<true, false, true, true><<<dim3(DD / 256, FC / 128, NB), blk512, GLDS, stream>>>(
        Wcc, XRT, bcc, VX, V4, SP3, FC, DD, FC, FC, FC, DD, 0, sFD, sFD);
    fold_bn<<<dim3(4), blk, 0, stream>>>(SP3, goc, boc, SSF, 1.0f / (float)(NB * DD));

    // 9. out = BNo(t); out dtype per FLAG
    bn_apply<false, false><<<egrid, blk, 0, stream>>>(
        V4, nullptr, nullptr, SSF, d_out, FLAG, PE / 4, 9, nullptr);
}

// Round 9
// 605.604 us; speedup vs baseline: 1.0763x; 1.0123x over previous
//
#include <hip/hip_runtime.h>
#include <stdint.h>

#define NB 32
#define FC 1024
#define DD 512
#define HH 1024
#define BN_EPS 1e-5f

typedef unsigned short u16;
typedef unsigned int u32;
typedef __attribute__((ext_vector_type(8))) short bf16x8;   // 8 bf16 = 4 VGPRs
typedef __attribute__((ext_vector_type(4))) float f32x4;
typedef __attribute__((ext_vector_type(8))) unsigned short ushort8v;

#define AS1 __attribute__((address_space(1)))
#define AS3 __attribute__((address_space(3)))

__device__ __forceinline__ float b2f(u16 u) {
    union { u32 i; float f; } v;
    v.i = ((u32)u) << 16;
    return v.f;
}
__device__ __forceinline__ u16 f2b(float f) {
    union { float f; u32 i; } v;
    v.f = f;
    const u32 b = v.i;
    return (u16)((b + 0x7FFFu + ((b >> 16) & 1u)) >> 16);
}

// async global->LDS, 16B per lane; lds dest must be wave-uniform base
__device__ __forceinline__ void gld16(const u16* g, u16* l) {
    __builtin_amdgcn_global_load_lds((const AS1 u32*)g, (AS3 u32*)l, 16, 0, 0);
}

// XCD-aware tile swizzle: lin%8 = XCD slab over (m,z); each XCD iterates n
// fastest within its slab -> A-tile reuse lands in one XCD's L2.
__device__ __forceinline__ void swizzle_tiles(int& mt, int& nt, int& zt) {
    const int gx = gridDim.x, gy = gridDim.y, gz = gridDim.z;
    const int mzTot = gy * gz;
    if ((mzTot & 7) != 0) { nt = blockIdx.x; mt = blockIdx.y; zt = blockIdx.z; return; }
    long lin = ((long)blockIdx.z * gy + blockIdx.y) * gx + blockIdx.x;
    const int slab = mzTot >> 3;
    const int xcd = (int)(lin & 7);
    const long idx = lin >> 3;
    nt = (int)(idx % gx);
    const int mz = (int)(idx / gx) + xcd * slab;
    mt = mz % gy;
    zt = mz / gy;
}

// ---------------------------------------------------------------------------
// init: zero the 4 stats-partial buffers (32 blocks x 256 floats = 8*FC) and
// (block 0) detect dtype: flag=1 if x is bf16 pairs, 0 if fp32.
// ---------------------------------------------------------------------------
__global__ __launch_bounds__(256) void init_detect(
    float* __restrict__ sp, const u32* __restrict__ x, int* __restrict__ flag)
{
    sp[blockIdx.x * 256 + threadIdx.x] = 0.0f;
    if (blockIdx.x != 0) return;
    __shared__ int cnt[256];
    int c = 0;
    for (int i = threadIdx.x; i < 4096; i += 256) {
        const u32 lo = x[i] & 0xFFFFu;
        const u32 e = (lo >> 7) & 0xFFu;
        if (e >= 0x68u && e <= 0x85u) c++;
    }
    cnt[threadIdx.x] = c;
    __syncthreads();
    for (int s = 128; s > 0; s >>= 1) {
        if (threadIdx.x < (unsigned)s) cnt[threadIdx.x] += cnt[threadIdx.x + s];
        __syncthreads();
    }
    if (threadIdx.x == 0) flag[0] = (cnt[0] > 2048) ? 1 : 0;
}

// fold (sum, sumsq) partials -> (scale, shift)
__global__ __launch_bounds__(256) void fold_bn(
    const float* __restrict__ sp, const u16* __restrict__ gamma,
    const u16* __restrict__ beta, float* __restrict__ ssf, float invCnt)
{
    const int f = blockIdx.x * 256 + threadIdx.x;
    if (f < FC) {
        const float mean = sp[f] * invCnt;
        const float var  = sp[FC + f] * invCnt - mean * mean;
        const float rstd = rsqrtf(var + BN_EPS);
        const float sc   = b2f(gamma[f]) * rstd;
        ssf[f]      = sc;
        ssf[FC + f] = b2f(beta[f]) - mean * sc;
    }
}

__global__ __launch_bounds__(256) void convert_to_bf16(
    const void* __restrict__ src, u16* __restrict__ dst, long n4,
    const int* __restrict__ flag)
{
    const bool isbf = (*flag != 0);
    long i4 = (long)blockIdx.x * blockDim.x + threadIdx.x;
    const long stride = (long)gridDim.x * blockDim.x;
    for (; i4 < n4; i4 += stride) {
        const long i = i4 << 2;
        if (isbf) {
            *(ushort4*)(dst + i) = *(const ushort4*)((const u16*)src + i);
        } else {
            const float4 v = *(const float4*)((const float*)src + i);
            ushort4 o;
            o.x = f2b(v.x); o.y = f2b(v.y); o.z = f2b(v.z); o.w = f2b(v.w);
            *(ushort4*)(dst + i) = o;
        }
    }
}

// all 14 params in one launch
struct ConvArgs { const void* src[14]; long off[14]; long n4[14]; };
__global__ __launch_bounds__(256) void convert_params(
    ConvArgs a, u16* __restrict__ dst, const int* __restrict__ flag)
{
    const bool isbf = (*flag != 0);
    const long stride = (long)gridDim.x * blockDim.x;
    for (int s = 0; s < 14; ++s) {
        const long n4 = a.n4[s];
        u16* d = dst + a.off[s];
        const void* sp = a.src[s];
        for (long i4 = (long)blockIdx.x * blockDim.x + threadIdx.x; i4 < n4;
             i4 += stride) {
            const long i = i4 << 2;
            if (isbf) {
                *(ushort4*)(d + i) = *(const ushort4*)((const u16*)sp + i);
            } else {
                const float4 v = *(const float4*)((const float*)sp + i);
                ushort4 o;
                o.x = f2b(v.x); o.y = f2b(v.y); o.z = f2b(v.z); o.w = f2b(v.w);
                *(ushort4*)(d + i) = o;
            }
        }
    }
}

// ---------------------------------------------------------------------------
// 128x256 MFMA GEMM (NT), BK=32, double-buffered (R4 structure -- best
// measured over 8 rounds). C[m][n]=sum_k A[m][k]*B[n][k]
//   (+bias, softsign, resid, fused BN stats).
// 512 thr = 8 waves (2M x 4N); per-wave 64x64 = 4x4 frags of 16x16x32.
// LDS 48 KiB (2 bufs x [A 8K + B 16K]) -> 2 blocks/CU. One __syncthreads per
// K-step; stage issued BEFORE reads. STATS: per-channel (sum,sumsq) via
// 4-lane shfl reduce + atomicAdd. RESID: +resid (C strides) pre-stats/store.
// All grids are multiples of 512 blocks (2 blocks/CU x 256 CU) -> no partial
// scheduling rounds (R7 lesson: partial fill costs a whole block-time).
// GEMM schedule frozen: 6 variants (drain/8-phase/3-ring/counted-vmcnt/
// 256thr-4blk/128sq) all pin at MfmaUtil 19-23% -- per-CU staging wall.
// LDS swizzle (both-sides, verified R1-R8): granule q ^= (r>>1)&3 on global
// source k-offset (gld16 dest linear) and on ds_read offset. Residual
// SQ_LDS_BANK_CONFLICT == 1 cyc per ds_read_b128 (2-way, ~free per m136).
// ---------------------------------------------------------------------------
template<bool BIAS, bool SOFTSIGN, bool STATS, bool RESID>
__global__ __launch_bounds__(512, 4) void gemm128x256_nt(
    const u16* __restrict__ A, const u16* __restrict__ B,
    const u16* __restrict__ bias, const u16* __restrict__ resid,
    u16* __restrict__ C, float* __restrict__ sp,
    int M, int N, int K, int lda, int ldb, int ldc,
    long sA, long sB, long sC)
{
    extern __shared__ char smem[];

    int mt, nt, zt;
    swizzle_tiles(mt, nt, zt);
    const u16* Ab = A + (long)zt * sA + (long)(mt * 128) * lda;
    const u16* Bb = B + (long)zt * sB + (long)(nt * 256) * ldb;
    C += (long)zt * sC;
    const u16* RP = RESID ? (resid + (long)zt * sC) : nullptr;

    const int tid  = threadIdx.x;
    const int lane = tid & 63;
    const int wv   = tid >> 6;          // 0..7
    const int wrr  = (wv >> 2) * 64;    // wave row offset in tile (0/64)
    const int wc   = (wv & 3) * 64;     // wave col offset in tile
    const int lm   = lane & 15;
    const int q    = lane >> 4;         // k-granule 0..3

    // ---- swizzled read byte-offsets (A region [128][32], B region [256][32])
    int aOff[4], bOff[4];
    #pragma unroll
    for (int i = 0; i < 4; ++i) {
        const int r = wrr + i * 16 + lm;
        aOff[i] = r * 64 + ((q ^ ((r >> 1) & 3)) << 4);
    }
    #pragma unroll
    for (int j = 0; j < 4; ++j) {
        const int r = wc + j * 16 + lm;
        bOff[j] = r * 64 + ((q ^ ((r >> 1) & 3)) << 4);
    }

    // ---- staging: 3 gld16/thread; gld16 dest linear, swizzle pre-applied to
    // the GLOBAL k-granule (involution == its own inverse).
    const int rw = lane >> 2, qs = lane & 3;
    const int rA  = wv * 16 + rw;
    const int rB0 = wv * 32 + rw;
    const int rB1 = wv * 32 + 16 + rw;
    const u16* pA  = Ab + (long)rA  * lda + ((qs ^ ((rA  >> 1) & 3)) << 3);
    const u16* pB0 = Bb + (long)rB0 * ldb + ((qs ^ ((rB0 >> 1) & 3)) << 3);
    const u16* pB1 = Bb + (long)rB1 * ldb + ((qs ^ ((rB1 >> 1) & 3)) << 3);
    const int ldsA  = wv * 1024;
    const int ldsB0 = wv * 2048;
    const int ldsB1 = wv * 2048 + 1024;

#define STAGE(bufOff, kofs) { \
    gld16(pA  + (kofs), (u16*)(smem + (bufOff) + ldsA)); \
    gld16(pB0 + (kofs), (u16*)(smem + (bufOff) + 8192 + ldsB0)); \
    gld16(pB1 + (kofs), (u16*)(smem + (bufOff) + 8192 + ldsB1)); }

    f32x4 acc[4][4] = {};

    const int NT = K >> 5;             // K-steps of 32

    STAGE(0, 0);
    __syncthreads();                   // tile 0 resident (vmcnt+lgkm drained)

    for (int t = 0; t < NT; ++t) {
        const int bo = (t & 1) * 24576;
        const int bn = ((t + 1) & 1) * 24576;
        if (t + 1 < NT) STAGE(bn, (t + 1) * 32);

        bf16x8 a[4], b[4];
        const char* baseA = smem + bo;
        const char* baseB = smem + bo + 8192;
        #pragma unroll
        for (int i = 0; i < 4; ++i) a[i] = *(const bf16x8*)(baseA + aOff[i]);
        #pragma unroll
        for (int j = 0; j < 4; ++j) b[j] = *(const bf16x8*)(baseB + bOff[j]);

        #pragma unroll
        for (int i = 0; i < 4; ++i)
            #pragma unroll
            for (int j = 0; j < 4; ++j)
                acc[i][j] = __builtin_amdgcn_mfma_f32_16x16x32_bf16(
                    a[i], b[j], acc[i][j], 0, 0, 0);

        __syncthreads();               // reads done + next tile resident
    }

#undef STAGE

    // epilogue: per-wave LDS repack (16x65 fp32 each), optional resid add,
    // optional fused BN stats, coalesced bf16 stores
    float* rep = (float*)smem + wv * (16 * 65);
    const int rr = lane >> 2;
    const int cg = lane & 3;
    const int m0 = mt * 128;
    const int n0 = nt * 256;
    #pragma unroll
    for (int i = 0; i < 4; ++i) {      // row-frag: row = wrr + 16*i
        #pragma unroll
        for (int j = 0; j < 4; ++j) {  // col-frag: col = wc + 16*j
            const int col = 16 * j + lm;
            const float bj = BIAS ? b2f(bias[n0 + wc + col]) : 0.0f;
            #pragma unroll
            for (int r = 0; r < 4; ++r) {
                float v = acc[i][j][r] + bj;
                if (SOFTSIGN) v = v / (1.0f + fabsf(v));
                rep[(q * 4 + r) * 65 + col] = v;
            }
        }
        // intra-wave LDS RAW/WAR: wave-lockstep + per-wave buffer
        const int row = m0 + wrr + 16 * i + rr;
        const float* lr = rep + rr * 65 + cg * 16;
        float4 f0 = *(const float4*)(lr + 0);
        float4 f1 = *(const float4*)(lr + 4);
        float4 f2 = *(const float4*)(lr + 8);
        float4 f3 = *(const float4*)(lr + 12);
        if (RESID) {
            const u16* rp = RP + (long)row * ldc + n0 + wc + cg * 16;
            const ushort8v ra = *(const ushort8v*)rp;
            const ushort8v rb = *(const ushort8v*)(rp + 8);
            f0.x += b2f(ra[0]); f0.y += b2f(ra[1]); f0.z += b2f(ra[2]); f0.w += b2f(ra[3]);
            f1.x += b2f(ra[4]); f1.y += b2f(ra[5]); f1.z += b2f(ra[6]); f1.w += b2f(ra[7]);
            f2.x += b2f(rb[0]); f2.y += b2f(rb[1]); f2.z += b2f(rb[2]); f2.w += b2f(rb[3]);
            f3.x += b2f(rb[4]); f3.y += b2f(rb[5]); f3.z += b2f(rb[6]); f3.w += b2f(rb[7]);
        }
        if (STATS) {
            float s1 = (f0.x + f0.y + f0.z + f0.w) + (f1.x + f1.y + f1.z + f1.w)
                     + (f2.x + f2.y + f2.z + f2.w) + (f3.x + f3.y + f3.z + f3.w);
            float s2 = f0.x*f0.x + f0.y*f0.y + f0.z*f0.z + f0.w*f0.w
                     + f1.x*f1.x + f1.y*f1.y + f1.z*f1.z + f1.w*f1.w
                     + f2.x*f2.x + f2.y*f2.y + f2.z*f2.z + f2.w*f2.w
                     + f3.x*f3.x + f3.y*f3.y + f3.z*f3.z + f3.w*f3.w;
            s1 += __shfl_xor(s1, 1); s1 += __shfl_xor(s1, 2);
            s2 += __shfl_xor(s2, 1); s2 += __shfl_xor(s2, 2);
            if (cg == 0) {
                const int ch = row & (FC - 1);
                atomicAdd(&sp[ch], s1);
                atomicAdd(&sp[FC + ch], s2);
            }
        }
        ushort8v o0, o1;
        o0[0] = f2b(f0.x); o0[1] = f2b(f0.y); o0[2] = f2b(f0.z); o0[3] = f2b(f0.w);
        o0[4] = f2b(f1.x); o0[5] = f2b(f1.y); o0[6] = f2b(f1.z); o0[7] = f2b(f1.w);
        o1[0] = f2b(f2.x); o1[1] = f2b(f2.y); o1[2] = f2b(f2.z); o1[3] = f2b(f2.w);
        o1[4] = f2b(f3.x); o1[5] = f2b(f3.y); o1[6] = f2b(f3.z); o1[7] = f2b(f3.w);
        u16* cp = C + (long)row * ldc + n0 + wc + cg * 16;
        *(ushort8v*)cp = o0;
        *(ushort8v*)(cp + 8) = o1;
    }
}

// ---------------------------------------------------------------------------
// VECTORIZED transpose fused with BN apply (G13: scalar bf16 global access is
// 2-2.5x slower -- old version was scalar on all three streams).
// Writes normalized value in-place (dstI) AND transposed (dstT).
// channel = source row (F dim). Bit-identical math to the scalar version
// (same fmaf/f2b per element); only the access pattern changes.
// 32x32 tile / 256 threads: thread (ly=t>>3, lx=t&7) loads ushort4
// src[r0+ly][c0+4lx..+3] (8B coalesced: 8 lanes cover 64 contiguous bytes),
// BN-applies, stores dstI ushort4, stores LDS [32][36] (u16, +4 pad).
// Out: thread packs t[4lx+k][ly], k=0..3 (4 scalar LDS reads, <=4-way bank)
// into one ushort4 store dstT[c0+ly][r0+4lx..+3] (8B coalesced).
// ---------------------------------------------------------------------------
__global__ __launch_bounds__(256) void transpose_bn_bf16(
    const u16* __restrict__ src, u16* __restrict__ dstT,
    u16* __restrict__ dstI, const float* __restrict__ ssf,
    int R, int Cc, long sS, long sD)
{
    __shared__ u16 t[32][36];
    const int bz = blockIdx.z;
    src  += (long)bz * sS;
    dstI += (long)bz * sS;
    dstT += (long)bz * sD;
    const int c0 = blockIdx.x * 32;
    const int r0 = blockIdx.y * 32;
    const int lx = threadIdx.x & 7;    // col-group (4 elems)
    const int ly = threadIdx.x >> 3;   // row 0..31

    const int r = r0 + ly;
    const float sc = ssf[r];
    const float sh = ssf[FC + r];
    const ushort4 v = *(const ushort4*)(src + (long)r * Cc + c0 + lx * 4);
    ushort4 nv;
    nv.x = f2b(fmaf(b2f(v.x), sc, sh));
    nv.y = f2b(fmaf(b2f(v.y), sc, sh));
    nv.z = f2b(fmaf(b2f(v.z), sc, sh));
    nv.w = f2b(fmaf(b2f(v.w), sc, sh));
    *(ushort4*)(dstI + (long)r * Cc + c0 + lx * 4) = nv;
    *(ushort4*)&t[ly][lx * 4] = nv;

    __syncthreads();

    const int oc = c0 + ly;            // dstT row = source col
    ushort4 o;
    o.x = t[lx * 4 + 0][ly];
    o.y = t[lx * 4 + 1][ly];
    o.z = t[lx * 4 + 2][ly];
    o.w = t[lx * 4 + 3][ly];
    *(ushort4*)(dstT + (long)oc * R + r0 + lx * 4) = o;
}

// dst = src*scale+shift (+ add); optional fused stats of the OUTPUT (fp32,
// pre-rounding): wave covers 256 contiguous elems = one channel at Lc=512.
template<bool ADD, bool STATS>
__global__ __launch_bounds__(256) void bn_apply(
    const u16* __restrict__ src, const void* __restrict__ add,
    const int* __restrict__ addflag,
    const float* __restrict__ ss, void* __restrict__ dst,
    const int* __restrict__ outflag, long total4, int lcShift,
    float* __restrict__ sp)
{
    const bool addf32 = ADD && (addflag != nullptr) && (*addflag == 0);
    const bool outf32 = (outflag != nullptr) && (*outflag == 0);
    long i4 = (long)blockIdx.x * blockDim.x + threadIdx.x;
    const long stride = (long)gridDim.x * blockDim.x;
    for (; i4 < total4; i4 += stride) {
        const long i = i4 << 2;
        const int c = (int)((i >> lcShift) & (FC - 1));
        const float sc = ss[c];
        const float sh = ss[FC + c];
        const ushort4 v = *(const ushort4*)(src + i);
        float o0 = fmaf(b2f(v.x), sc, sh);
        float o1 = fmaf(b2f(v.y), sc, sh);
        float o2 = fmaf(b2f(v.z), sc, sh);
        float o3 = fmaf(b2f(v.w), sc, sh);
        if (ADD) {
            if (addf32) {
                const float4 a = *(const float4*)((const float*)add + i);
                o0 += a.x; o1 += a.y; o2 += a.z; o3 += a.w;
            } else {
                const ushort4 a = *(const ushort4*)((const u16*)add + i);
                o0 += b2f(a.x); o1 += b2f(a.y); o2 += b2f(a.z); o3 += b2f(a.w);
            }
        }
        if (STATS) {
            float s1 = o0 + o1 + o2 + o3;
            float s2 = o0 * o0 + o1 * o1 + o2 * o2 + o3 * o3;
            #pragma unroll
            for (int m = 1; m < 64; m <<= 1) {
                s1 += __shfl_xor(s1, m);
                s2 += __shfl_xor(s2, m);
            }
            if ((threadIdx.x & 63) == 0) {
                atomicAdd(&sp[c], s1);
                atomicAdd(&sp[FC + c], s2);
            }
        }
        if (outf32) {
            float4 o; o.x = o0; o.y = o1; o.z = o2; o.w = o3;
            *(float4*)((float*)dst + i) = o;
        } else {
            ushort4 o;
            o.x = f2b(o0); o.y = f2b(o1); o.z = f2b(o2); o.w = f2b(o3);
            *(ushort4*)((u16*)dst + i) = o;
        }
    }
}

extern "C" void kernel_launch(void* const* d_in, const int* in_sizes, int n_in,
                              void* d_out, int out_size, void* d_ws, size_t ws_size,
                              hipStream_t stream)
{
    const size_t MiB = (size_t)1 << 20;
    const long sFH = (long)FC * HH;        // 1,048,576 elems (2 MiB bf16)
    const long sFF = (long)FC * FC;        // 1,048,576
    const long sFD = (long)FC * DD;        //   524,288 (1 MiB)
    const long PE  = (long)NB * FC * DD;   // 16,777,216 (32 MiB)

    const size_t GLDS = 49152;             // 48 KiB dynamic LDS -> 2 blocks/CU
    static bool s_attr = false;
    if (!s_attr) {
        s_attr = true;
        hipFuncSetAttribute(reinterpret_cast<const void*>(&gemm128x256_nt<true, false, true, false>),
                            hipFuncAttributeMaxDynamicSharedMemorySize, (int)GLDS);
        hipFuncSetAttribute(reinterpret_cast<const void*>(&gemm128x256_nt<false, true, false, false>),
                            hipFuncAttributeMaxDynamicSharedMemorySize, (int)GLDS);
        hipFuncSetAttribute(reinterpret_cast<const void*>(&gemm128x256_nt<false, false, false, false>),
                            hipFuncAttributeMaxDynamicSharedMemorySize, (int)GLDS);
        hipFuncSetAttribute(reinterpret_cast<const void*>(&gemm128x256_nt<true, false, true, true>),
                            hipFuncAttributeMaxDynamicSharedMemorySize, (int)GLDS);
    }

    // bf16 param packing offsets
    long off[16];
    long cur = 0;
    for (int i = 1; i < 15; ++i) { off[i] = cur; cur += ((long)in_sizes[i] + 7) & ~7L; }
    const size_t paramBytes = (size_t)cur * 2;

    // adaptive correlation chunk: scratch = cb*6 MiB (VT + W + V2)
    int cb = 32;
    while (cb > 1 &&
           64 * MiB + (size_t)cb * 6 * MiB + paramBytes + 65536 > ws_size)
        cb >>= 1;

    // ---- workspace layout ----
    u16* V   = (u16*)d_ws;                          // 64 MiB: v (N,F,H)
    u16* VT  = (u16*)((char*)d_ws + 64 * MiB);      // cb*2 MiB: v^T chunk
    u16* WW  = VT + (long)cb * sFH;                 // cb*2 MiB: w chunk
    u16* V2  = WW + (long)cb * sFF;                 // cb*2 MiB: v2 chunk
    u16* WC  = V2 + (long)cb * sFH;                 // packed bf16 params
    char* tail = (char*)(WC + cur);
    tail = (char*)(((uintptr_t)tail + 255) & ~(uintptr_t)255);
    float* SP0  = (float*)tail;                     // 4 stage partial buffers
    float* SP1  = SP0 + 2 * FC;
    float* SP2  = SP1 + 2 * FC;
    float* SP3  = SP2 + 2 * FC;
    float* SSF  = SP3 + 2 * FC;                     // folded (scale,shift)
    int*   FLAG = (int*)(SSF + 2 * FC);
    // d_out (fp32 out => 64 MiB): lower 32 MiB = VX (v3->s->xr), upper = XB
    u16* VX  = (u16*)d_out;
    u16* XB  = (u16*)d_out + PE;                    // x as bf16
    u16* V4  = V;                                   // v4/t (N,F,D) reuses V
    u16* XRT = V + PE;                              // xr^T reuses V upper half

    const dim3 blk(256);
    const dim3 blk512(512);
    const dim3 egrid(4096);

    // 0. zero stats partials + detect dtype (one dispatch); convert params + x
    init_detect<<<dim3(32), blk, 0, stream>>>(SP0, (const u32*)d_in[0], FLAG);
    ConvArgs ca;
    for (int i = 1; i < 15; ++i) {
        ca.src[i - 1] = d_in[i];
        ca.off[i - 1] = off[i];
        ca.n4[i - 1]  = (long)in_sizes[i] / 4;
    }
    convert_params<<<dim3(256), blk, 0, stream>>>(ca, WC, FLAG);
    convert_to_bf16<<<dim3(1024), blk, 0, stream>>>(d_in[0], XB, PE / 4, FLAG);

    const u16* W0c = WC + off[1];
    const u16* b0c = WC + off[2];
    const u16* g0c = WC + off[3];
    const u16* be0c = WC + off[4];
    const u16* W1c = WC + off[5];
    const u16* b1c = WC + off[6];
    const u16* g1c = WC + off[7];
    const u16* be1c = WC + off[8];
    const u16* gfc = WC + off[9];
    const u16* bfc = WC + off[10];
    const u16* Wcc = WC + off[11];
    const u16* bcc = WC + off[12];
    const u16* goc = WC + off[13];
    const u16* boc = WC + off[14];

    // 1. v = x @ W0^T + b0  (BN0 stats fused into epilogue -> SP0)
    gemm128x256_nt<true, false, true, false><<<dim3(HH / 256, (NB * FC) / 128, 1), blk512, GLDS, stream>>>(
        XB, W0c, b0c, nullptr, V, SP0, NB * FC, HH, DD, DD, DD, HH, 0, 0, 0);
    fold_bn<<<dim3(4), blk, 0, stream>>>(SP0, g0c, be0c, SSF, 1.0f / (float)(NB * HH));

    // 2-5 per chunk: vT+BN0-apply (V in place + VT); w = softsign(v v^T);
    // v2 = w @ v (via vT); v3 = v2 @ W1^T + b1 (BN1 stats fused -> SP1)
    for (int bz0 = 0; bz0 < NB; bz0 += cb) {
        const int c = (NB - bz0 < cb) ? (NB - bz0) : cb;
        transpose_bn_bf16<<<dim3(HH / 32, FC / 32, c), blk, 0, stream>>>(
            V + bz0 * sFH, VT, V + bz0 * sFH, SSF, FC, HH, sFH, sFH);
        gemm128x256_nt<false, true, false, false><<<dim3(FC / 256, FC / 128, c), blk512, GLDS, stream>>>(
            V + bz0 * sFH, V + bz0 * sFH, nullptr, nullptr, WW, nullptr,
            FC, FC, HH, HH, HH, FC, sFH, sFH, sFF);
        gemm128x256_nt<false, false, false, false><<<dim3(HH / 256, FC / 128, c), blk512, GLDS, stream>>>(
            WW, VT, nullptr, nullptr, V2, nullptr,
            FC, HH, FC, FC, FC, HH, sFF, sFH, sFH);
        gemm128x256_nt<true, false, true, false><<<dim3(DD / 256, (c * FC) / 128, 1), blk512, GLDS, stream>>>(
            V2, W1c, b1c, nullptr, VX + bz0 * sFD, SP1,
            c * FC, DD, HH, HH, HH, DD, 0, 0, 0);
    }
    fold_bn<<<dim3(4), blk, 0, stream>>>(SP1, g1c, be1c, SSF, 1.0f / (float)(NB * DD));

    // 6. s = BN1(v3) + x   (in place VX; s-stats for BNf fused -> SP2)
    bn_apply<true, true><<<egrid, blk, 0, stream>>>(
        VX, XB, nullptr, SSF, VX, nullptr, PE / 4, 9, SP2);
    fold_bn<<<dim3(4), blk, 0, stream>>>(SP2, gfc, bfc, SSF, 1.0f / (float)(NB * DD));

    // 7. xr = BNf(s) fused into xr^T transpose (in-place VX + XRT)
    transpose_bn_bf16<<<dim3(DD / 32, FC / 32, NB), blk, 0, stream>>>(
        VX, XRT, VX, SSF, FC, DD, sFD, sFD);

    // 8. t = Wc @ xr + bc + xr (resid+bias+BNo-stats fused) -> V4
    gemm128x256_nt<true, false, true, true><<<dim3(DD / 256, FC / 128, NB), blk512, GLDS, stream>>>(
        Wcc, XRT, bcc, VX, V4, SP3, FC, DD, FC, FC, FC, DD, 0, sFD, sFD);
    fold_bn<<<dim3(4), blk, 0, stream>>>(SP3, goc, boc, SSF, 1.0f / (float)(NB * DD));

    // 9. out = BNo(t); out dtype per FLAG
    bn_apply<false, false><<<egrid, blk, 0, stream>>>(
        V4, nullptr, nullptr, SSF, d_out, FLAG, PE / 4, 9, nullptr);
}

// Round 10
// 591.504 us; speedup vs baseline: 1.1019x; 1.0238x over previous
//
#include <hip/hip_runtime.h>
#include <stdint.h>

#define NB 32
#define FC 1024
#define DD 512
#define HH 1024
#define BN_EPS 1e-5f

typedef unsigned short u16;
typedef unsigned int u32;
typedef __attribute__((ext_vector_type(8))) short bf16x8;   // 8 bf16 = 4 VGPRs
typedef __attribute__((ext_vector_type(4))) float f32x4;
typedef __attribute__((ext_vector_type(8))) unsigned short ushort8v;

#define AS1 __attribute__((address_space(1)))
#define AS3 __attribute__((address_space(3)))

__device__ __forceinline__ float b2f(u16 u) {
    union { u32 i; float f; } v;
    v.i = ((u32)u) << 16;
    return v.f;
}
__device__ __forceinline__ u16 f2b(float f) {
    union { float f; u32 i; } v;
    v.f = f;
    const u32 b = v.i;
    return (u16)((b + 0x7FFFu + ((b >> 16) & 1u)) >> 16);
}

// async global->LDS, 16B per lane; lds dest must be wave-uniform base
__device__ __forceinline__ void gld16(const u16* g, u16* l) {
    __builtin_amdgcn_global_load_lds((const AS1 u32*)g, (AS3 u32*)l, 16, 0, 0);
}

// XCD-aware tile swizzle: lin%8 = XCD slab over (m,z); each XCD iterates n
// fastest within its slab -> A-tile reuse lands in one XCD's L2.
__device__ __forceinline__ void swizzle_tiles(int& mt, int& nt, int& zt) {
    const int gx = gridDim.x, gy = gridDim.y, gz = gridDim.z;
    const int mzTot = gy * gz;
    if ((mzTot & 7) != 0) { nt = blockIdx.x; mt = blockIdx.y; zt = blockIdx.z; return; }
    long lin = ((long)blockIdx.z * gy + blockIdx.y) * gx + blockIdx.x;
    const int slab = mzTot >> 3;
    const int xcd = (int)(lin & 7);
    const long idx = lin >> 3;
    nt = (int)(idx % gx);
    const int mz = (int)(idx / gx) + xcd * slab;
    mt = mz % gy;
    zt = mz / gy;
}

// ---------------------------------------------------------------------------
// init: zero the stats-partial region (9*FC floats = 36 blocks x 256) and
// (block 0) detect dtype: flag=1 if x is bf16 pairs, 0 if fp32.
// ---------------------------------------------------------------------------
__global__ __launch_bounds__(256) void init_detect(
    float* __restrict__ sp, const u32* __restrict__ x, int* __restrict__ flag)
{
    sp[blockIdx.x * 256 + threadIdx.x] = 0.0f;
    if (blockIdx.x != 0) return;
    __shared__ int cnt[256];
    int c = 0;
    for (int i = threadIdx.x; i < 4096; i += 256) {
        const u32 lo = x[i] & 0xFFFFu;
        const u32 e = (lo >> 7) & 0xFFu;
        if (e >= 0x68u && e <= 0x85u) c++;
    }
    cnt[threadIdx.x] = c;
    __syncthreads();
    for (int s = 128; s > 0; s >>= 1) {
        if (threadIdx.x < (unsigned)s) cnt[threadIdx.x] += cnt[threadIdx.x + s];
        __syncthreads();
    }
    if (threadIdx.x == 0) flag[0] = (cnt[0] > 2048) ? 1 : 0;
}

// fold (sum, sumsq) partials -> (scale, shift)
__global__ __launch_bounds__(256) void fold_bn(
    const float* __restrict__ sp, const u16* __restrict__ gamma,
    const u16* __restrict__ beta, float* __restrict__ ssf, float invCnt)
{
    const int f = blockIdx.x * 256 + threadIdx.x;
    if (f < FC) {
        const float mean = sp[f] * invCnt;
        const float var  = sp[FC + f] * invCnt - mean * mean;
        const float rstd = rsqrtf(var + BN_EPS);
        const float sc   = b2f(gamma[f]) * rstd;
        ssf[f]      = sc;
        ssf[FC + f] = b2f(beta[f]) - mean * sc;
    }
}

// ---------------------------------------------------------------------------
// fold BN1 from v3 partials, then ANALYTICALLY derive BNf stats of
// s = sc1*v3 + sh1 + x (never materialized):
//   Sum_s  = sc1*S1v + cnt*sh1 + S1x
//   Sum_s2 = sc1^2*S2v + 2*sc1*sh1*S1v + cnt*sh1^2 + 2*sc1*Sxv + 2*sh1*S1x + S2x
// sp1 layout: [S1v | S2v | Sxv] (3*FC); spx: [S1x | S2x] (2*FC).
// ssd out: [sc1 | sh1 | scf | shf] (4*FC).
// ---------------------------------------------------------------------------
__global__ __launch_bounds__(256) void fold2_bn(
    const float* __restrict__ sp1, const float* __restrict__ spx,
    const u16* __restrict__ g1, const u16* __restrict__ be1,
    const u16* __restrict__ gf, const u16* __restrict__ bf_,
    float* __restrict__ ssd, float cnt)
{
    const int f = blockIdx.x * 256 + threadIdx.x;
    if (f >= FC) return;
    const float inv  = 1.0f / cnt;
    const float S1v = sp1[f], S2v = sp1[FC + f], Sxv = sp1[2 * FC + f];
    const float mean1 = S1v * inv;
    const float var1  = S2v * inv - mean1 * mean1;
    const float sc1   = b2f(g1[f]) * rsqrtf(var1 + BN_EPS);
    const float sh1   = b2f(be1[f]) - mean1 * sc1;
    ssd[f]      = sc1;
    ssd[FC + f] = sh1;
    const float S1x = spx[f], S2x = spx[FC + f];
    const float sums = sc1 * S1v + cnt * sh1 + S1x;
    const float sss  = sc1 * sc1 * S2v + 2.f * sc1 * sh1 * S1v
                     + cnt * sh1 * sh1 + 2.f * sc1 * Sxv
                     + 2.f * sh1 * S1x + S2x;
    const float means = sums * inv;
    const float vars  = sss * inv - means * means;
    const float scf   = b2f(gf[f]) * rsqrtf(vars + BN_EPS);
    const float shf   = b2f(bf_[f]) - means * scf;
    ssd[2 * FC + f] = scf;
    ssd[3 * FC + f] = shf;
}

// ---------------------------------------------------------------------------
// convert x -> bf16 AND accumulate per-channel (sum, sumsq) of the ROUNDED
// values (matching what downstream bf16 reads would sum). Layout (N,F,D):
// channel = (i>>9)&1023; a wave's 256 contiguous elems stay in one channel
// (D=512, chunks 256-aligned) -> full-wave shfl reduce, 1 atomic pair/wave.
// ---------------------------------------------------------------------------
__global__ __launch_bounds__(256) void convert_x_stats(
    const void* __restrict__ src, u16* __restrict__ dst, long n4,
    const int* __restrict__ flag, float* __restrict__ spx)
{
    const bool isbf = (*flag != 0);
    long i4 = (long)blockIdx.x * blockDim.x + threadIdx.x;
    const long stride = (long)gridDim.x * blockDim.x;
    for (; i4 < n4; i4 += stride) {
        const long i = i4 << 2;
        ushort4 o;
        if (isbf) {
            o = *(const ushort4*)((const u16*)src + i);
        } else {
            const float4 v = *(const float4*)((const float*)src + i);
            o.x = f2b(v.x); o.y = f2b(v.y); o.z = f2b(v.z); o.w = f2b(v.w);
        }
        *(ushort4*)(dst + i) = o;
        const float a = b2f(o.x), b = b2f(o.y), c = b2f(o.z), d = b2f(o.w);
        float s1 = a + b + c + d;
        float s2 = a * a + b * b + c * c + d * d;
        #pragma unroll
        for (int m = 1; m < 64; m <<= 1) {
            s1 += __shfl_xor(s1, m);
            s2 += __shfl_xor(s2, m);
        }
        if ((threadIdx.x & 63) == 0) {
            const int ch = (int)((i >> 9) & (FC - 1));
            atomicAdd(&spx[ch], s1);
            atomicAdd(&spx[FC + ch], s2);
        }
    }
}

// all 14 params in one launch
struct ConvArgs { const void* src[14]; long off[14]; long n4[14]; };
__global__ __launch_bounds__(256) void convert_params(
    ConvArgs a, u16* __restrict__ dst, const int* __restrict__ flag)
{
    const bool isbf = (*flag != 0);
    const long stride = (long)gridDim.x * blockDim.x;
    for (int s = 0; s < 14; ++s) {
        const long n4 = a.n4[s];
        u16* d = dst + a.off[s];
        const void* sp = a.src[s];
        for (long i4 = (long)blockIdx.x * blockDim.x + threadIdx.x; i4 < n4;
             i4 += stride) {
            const long i = i4 << 2;
            if (isbf) {
                *(ushort4*)(d + i) = *(const ushort4*)((const u16*)sp + i);
            } else {
                const float4 v = *(const float4*)((const float*)sp + i);
                ushort4 o;
                o.x = f2b(v.x); o.y = f2b(v.y); o.z = f2b(v.z); o.w = f2b(v.w);
                *(ushort4*)(d + i) = o;
            }
        }
    }
}

// ---------------------------------------------------------------------------
// 128x256 MFMA GEMM (NT), BK=32, double-buffered (R4 structure -- best
// measured over 9 rounds). C[m][n]=sum_k A[m][k]*B[n][k]
//   (+bias, softsign, resid, fused BN stats, optional Sxv cross-stats).
// 512 thr = 8 waves (2M x 4N); per-wave 64x64 = 4x4 frags of 16x16x32.
// LDS 48 KiB (2 bufs x [A 8K + B 16K]) -> 2 blocks/CU. One __syncthreads per
// K-step; stage issued BEFORE reads. STATS: per-channel (sum,sumsq) via
// 4-lane shfl reduce + atomicAdd. RESID: +resid (C strides) pre-stats/store.
// XSTAT: read xres tile (C strides, NOT added) and accumulate
// sp[2FC+ch] += sum(out*x) -- enables analytic BNf stats (fold2_bn).
// GEMM schedule frozen: 6 variants all pin at MfmaUtil 19-23%.
// LDS swizzle (both-sides, verified R1-R9): granule q ^= (r>>1)&3 on global
// source k-offset (gld16 dest linear) and on ds_read offset.
// ---------------------------------------------------------------------------
template<bool BIAS, bool SOFTSIGN, bool STATS, bool RESID, bool XSTAT>
__global__ __launch_bounds__(512, 4) void gemm128x256_nt(
    const u16* __restrict__ A, const u16* __restrict__ B,
    const u16* __restrict__ bias, const u16* __restrict__ resid,
    u16* __restrict__ C, float* __restrict__ sp,
    int M, int N, int K, int lda, int ldb, int ldc,
    long sA, long sB, long sC)
{
    extern __shared__ char smem[];

    int mt, nt, zt;
    swizzle_tiles(mt, nt, zt);
    const u16* Ab = A + (long)zt * sA + (long)(mt * 128) * lda;
    const u16* Bb = B + (long)zt * sB + (long)(nt * 256) * ldb;
    C += (long)zt * sC;
    const u16* RP = (RESID || XSTAT) ? (resid + (long)zt * sC) : nullptr;

    const int tid  = threadIdx.x;
    const int lane = tid & 63;
    const int wv   = tid >> 6;          // 0..7
    const int wrr  = (wv >> 2) * 64;    // wave row offset in tile (0/64)
    const int wc   = (wv & 3) * 64;     // wave col offset in tile
    const int lm   = lane & 15;
    const int q    = lane >> 4;         // k-granule 0..3

    // ---- swizzled read byte-offsets (A region [128][32], B region [256][32])
    int aOff[4], bOff[4];
    #pragma unroll
    for (int i = 0; i < 4; ++i) {
        const int r = wrr + i * 16 + lm;
        aOff[i] = r * 64 + ((q ^ ((r >> 1) & 3)) << 4);
    }
    #pragma unroll
    for (int j = 0; j < 4; ++j) {
        const int r = wc + j * 16 + lm;
        bOff[j] = r * 64 + ((q ^ ((r >> 1) & 3)) << 4);
    }

    // ---- staging: 3 gld16/thread; gld16 dest linear, swizzle pre-applied to
    // the GLOBAL k-granule (involution == its own inverse).
    const int rw = lane >> 2, qs = lane & 3;
    const int rA  = wv * 16 + rw;
    const int rB0 = wv * 32 + rw;
    const int rB1 = wv * 32 + 16 + rw;
    const u16* pA  = Ab + (long)rA  * lda + ((qs ^ ((rA  >> 1) & 3)) << 3);
    const u16* pB0 = Bb + (long)rB0 * ldb + ((qs ^ ((rB0 >> 1) & 3)) << 3);
    const u16* pB1 = Bb + (long)rB1 * ldb + ((qs ^ ((rB1 >> 1) & 3)) << 3);
    const int ldsA  = wv * 1024;
    const int ldsB0 = wv * 2048;
    const int ldsB1 = wv * 2048 + 1024;

#define STAGE(bufOff, kofs) { \
    gld16(pA  + (kofs), (u16*)(smem + (bufOff) + ldsA)); \
    gld16(pB0 + (kofs), (u16*)(smem + (bufOff) + 8192 + ldsB0)); \
    gld16(pB1 + (kofs), (u16*)(smem + (bufOff) + 8192 + ldsB1)); }

    f32x4 acc[4][4] = {};

    const int NT = K >> 5;             // K-steps of 32

    STAGE(0, 0);
    __syncthreads();                   // tile 0 resident (vmcnt+lgkm drained)

    for (int t = 0; t < NT; ++t) {
        const int bo = (t & 1) * 24576;
        const int bn = ((t + 1) & 1) * 24576;
        if (t + 1 < NT) STAGE(bn, (t + 1) * 32);

        bf16x8 a[4], b[4];
        const char* baseA = smem + bo;
        const char* baseB = smem + bo + 8192;
        #pragma unroll
        for (int i = 0; i < 4; ++i) a[i] = *(const bf16x8*)(baseA + aOff[i]);
        #pragma unroll
        for (int j = 0; j < 4; ++j) b[j] = *(const bf16x8*)(baseB + bOff[j]);

        #pragma unroll
        for (int i = 0; i < 4; ++i)
            #pragma unroll
            for (int j = 0; j < 4; ++j)
                acc[i][j] = __builtin_amdgcn_mfma_f32_16x16x32_bf16(
                    a[i], b[j], acc[i][j], 0, 0, 0);

        __syncthreads();               // reads done + next tile resident
    }

#undef STAGE

    // epilogue: per-wave LDS repack (16x65 fp32 each), optional resid add,
    // optional fused BN stats (+Sxv), coalesced bf16 stores
    float* rep = (float*)smem + wv * (16 * 65);
    const int rr = lane >> 2;
    const int cg = lane & 3;
    const int m0 = mt * 128;
    const int n0 = nt * 256;
    #pragma unroll
    for (int i = 0; i < 4; ++i) {      // row-frag: row = wrr + 16*i
        #pragma unroll
        for (int j = 0; j < 4; ++j) {  // col-frag: col = wc + 16*j
            const int col = 16 * j + lm;
            const float bj = BIAS ? b2f(bias[n0 + wc + col]) : 0.0f;
            #pragma unroll
            for (int r = 0; r < 4; ++r) {
                float v = acc[i][j][r] + bj;
                if (SOFTSIGN) v = v / (1.0f + fabsf(v));
                rep[(q * 4 + r) * 65 + col] = v;
            }
        }
        // intra-wave LDS RAW/WAR: wave-lockstep + per-wave buffer
        const int row = m0 + wrr + 16 * i + rr;
        const float* lr = rep + rr * 65 + cg * 16;
        float4 f0 = *(const float4*)(lr + 0);
        float4 f1 = *(const float4*)(lr + 4);
        float4 f2 = *(const float4*)(lr + 8);
        float4 f3 = *(const float4*)(lr + 12);
        ushort8v ra, rb;
        if (RESID || XSTAT) {
            const u16* rp = RP + (long)row * ldc + n0 + wc + cg * 16;
            ra = *(const ushort8v*)rp;
            rb = *(const ushort8v*)(rp + 8);
        }
        if (RESID) {
            f0.x += b2f(ra[0]); f0.y += b2f(ra[1]); f0.z += b2f(ra[2]); f0.w += b2f(ra[3]);
            f1.x += b2f(ra[4]); f1.y += b2f(ra[5]); f1.z += b2f(ra[6]); f1.w += b2f(ra[7]);
            f2.x += b2f(rb[0]); f2.y += b2f(rb[1]); f2.z += b2f(rb[2]); f2.w += b2f(rb[3]);
            f3.x += b2f(rb[4]); f3.y += b2f(rb[5]); f3.z += b2f(rb[6]); f3.w += b2f(rb[7]);
        }
        if (STATS) {
            float s1 = (f0.x + f0.y + f0.z + f0.w) + (f1.x + f1.y + f1.z + f1.w)
                     + (f2.x + f2.y + f2.z + f2.w) + (f3.x + f3.y + f3.z + f3.w);
            float s2 = f0.x*f0.x + f0.y*f0.y + f0.z*f0.z + f0.w*f0.w
                     + f1.x*f1.x + f1.y*f1.y + f1.z*f1.z + f1.w*f1.w
                     + f2.x*f2.x + f2.y*f2.y + f2.z*f2.z + f2.w*f2.w
                     + f3.x*f3.x + f3.y*f3.y + f3.z*f3.z + f3.w*f3.w;
            float sxv = 0.0f;
            if (XSTAT) {
                sxv = f0.x*b2f(ra[0]) + f0.y*b2f(ra[1]) + f0.z*b2f(ra[2]) + f0.w*b2f(ra[3])
                    + f1.x*b2f(ra[4]) + f1.y*b2f(ra[5]) + f1.z*b2f(ra[6]) + f1.w*b2f(ra[7])
                    + f2.x*b2f(rb[0]) + f2.y*b2f(rb[1]) + f2.z*b2f(rb[2]) + f2.w*b2f(rb[3])
                    + f3.x*b2f(rb[4]) + f3.y*b2f(rb[5]) + f3.z*b2f(rb[6]) + f3.w*b2f(rb[7]);
            }
            s1 += __shfl_xor(s1, 1); s1 += __shfl_xor(s1, 2);
            s2 += __shfl_xor(s2, 1); s2 += __shfl_xor(s2, 2);
            if (XSTAT) { sxv += __shfl_xor(sxv, 1); sxv += __shfl_xor(sxv, 2); }
            if (cg == 0) {
                const int ch = row & (FC - 1);
                atomicAdd(&sp[ch], s1);
                atomicAdd(&sp[FC + ch], s2);
                if (XSTAT) atomicAdd(&sp[2 * FC + ch], sxv);
            }
        }
        ushort8v o0, o1;
        o0[0] = f2b(f0.x); o0[1] = f2b(f0.y); o0[2] = f2b(f0.z); o0[3] = f2b(f0.w);
        o0[4] = f2b(f1.x); o0[5] = f2b(f1.y); o0[6] = f2b(f1.z); o0[7] = f2b(f1.w);
        o1[0] = f2b(f2.x); o1[1] = f2b(f2.y); o1[2] = f2b(f2.z); o1[3] = f2b(f2.w);
        o1[4] = f2b(f3.x); o1[5] = f2b(f3.y); o1[6] = f2b(f3.z); o1[7] = f2b(f3.w);
        u16* cp = C + (long)row * ldc + n0 + wc + cg * 16;
        *(ushort8v*)cp = o0;
        *(ushort8v*)(cp + 8) = o1;
    }
}

// ---------------------------------------------------------------------------
// VECTORIZED transpose fused with BN apply (verified R9: ~2x vs scalar).
// Writes normalized value in-place (dstI) AND transposed (dstT).
// channel = source row. 32x32 tile / 256 threads; ushort4 on all global
// streams; LDS [32][36] u16 (+4 pad); out packs 4 LDS reads -> 1 ushort4.
// ---------------------------------------------------------------------------
__global__ __launch_bounds__(256) void transpose_bn_bf16(
    const u16* __restrict__ src, u16* __restrict__ dstT,
    u16* __restrict__ dstI, const float* __restrict__ ssf,
    int R, int Cc, long sS, long sD)
{
    __shared__ u16 t[32][36];
    const int bz = blockIdx.z;
    src  += (long)bz * sS;
    dstI += (long)bz * sS;
    dstT += (long)bz * sD;
    const int c0 = blockIdx.x * 32;
    const int r0 = blockIdx.y * 32;
    const int lx = threadIdx.x & 7;    // col-group (4 elems)
    const int ly = threadIdx.x >> 3;   // row 0..31

    const int r = r0 + ly;
    const float sc = ssf[r];
    const float sh = ssf[FC + r];
    const ushort4 v = *(const ushort4*)(src + (long)r * Cc + c0 + lx * 4);
    ushort4 nv;
    nv.x = f2b(fmaf(b2f(v.x), sc, sh));
    nv.y = f2b(fmaf(b2f(v.y), sc, sh));
    nv.z = f2b(fmaf(b2f(v.z), sc, sh));
    nv.w = f2b(fmaf(b2f(v.w), sc, sh));
    *(ushort4*)(dstI + (long)r * Cc + c0 + lx * 4) = nv;
    *(ushort4*)&t[ly][lx * 4] = nv;

    __syncthreads();

    const int oc = c0 + ly;            // dstT row = source col
    ushort4 o;
    o.x = t[lx * 4 + 0][ly];
    o.y = t[lx * 4 + 1][ly];
    o.z = t[lx * 4 + 2][ly];
    o.w = t[lx * 4 + 3][ly];
    *(ushort4*)(dstT + (long)oc * R + r0 + lx * 4) = o;
}

// ---------------------------------------------------------------------------
// DOUBLE-BN fused transpose: xr = scf*(sc1*v3 + sh1 + x) + shf, computed in
// fp32 (s never materialized), written in-place (dstI) and transposed (dstT).
// ssd layout: [sc1 | sh1 | scf | shf] (4*FC). channel = source row.
// ---------------------------------------------------------------------------
__global__ __launch_bounds__(256) void transpose_bn2_bf16(
    const u16* __restrict__ v3, const u16* __restrict__ x,
    u16* __restrict__ dstT, u16* __restrict__ dstI,
    const float* __restrict__ ssd, int R, int Cc, long sS, long sD)
{
    __shared__ u16 t[32][36];
    const int bz = blockIdx.z;
    v3   += (long)bz * sS;
    x    += (long)bz * sS;
    dstI += (long)bz * sS;
    dstT += (long)bz * sD;
    const int c0 = blockIdx.x * 32;
    const int r0 = blockIdx.y * 32;
    const int lx = threadIdx.x & 7;
    const int ly = threadIdx.x >> 3;

    const int r = r0 + ly;
    const float sc1 = ssd[r];
    const float sh1 = ssd[FC + r];
    const float scf = ssd[2 * FC + r];
    const float shf = ssd[3 * FC + r];
    const long base = (long)r * Cc + c0 + lx * 4;
    const ushort4 v  = *(const ushort4*)(v3 + base);
    const ushort4 xv = *(const ushort4*)(x + base);
    ushort4 nv;
    float s;
    s = fmaf(b2f(v.x), sc1, sh1) + b2f(xv.x); nv.x = f2b(fmaf(s, scf, shf));
    s = fmaf(b2f(v.y), sc1, sh1) + b2f(xv.y); nv.y = f2b(fmaf(s, scf, shf));
    s = fmaf(b2f(v.z), sc1, sh1) + b2f(xv.z); nv.z = f2b(fmaf(s, scf, shf));
    s = fmaf(b2f(v.w), sc1, sh1) + b2f(xv.w); nv.w = f2b(fmaf(s, scf, shf));
    *(ushort4*)(dstI + base) = nv;
    *(ushort4*)&t[ly][lx * 4] = nv;

    __syncthreads();

    const int oc = c0 + ly;
    ushort4 o;
    o.x = t[lx * 4 + 0][ly];
    o.y = t[lx * 4 + 1][ly];
    o.z = t[lx * 4 + 2][ly];
    o.w = t[lx * 4 + 3][ly];
    *(ushort4*)(dstT + (long)oc * R + r0 + lx * 4) = o;
}

// dst = src*scale+shift; dst dtype per outflag (final BNo apply)
__global__ __launch_bounds__(256) void bn_apply(
    const u16* __restrict__ src, const float* __restrict__ ss,
    void* __restrict__ dst, const int* __restrict__ outflag,
    long total4, int lcShift)
{
    const bool outf32 = (outflag != nullptr) && (*outflag == 0);
    long i4 = (long)blockIdx.x * blockDim.x + threadIdx.x;
    const long stride = (long)gridDim.x * blockDim.x;
    for (; i4 < total4; i4 += stride) {
        const long i = i4 << 2;
        const int c = (int)((i >> lcShift) & (FC - 1));
        const float sc = ss[c];
        const float sh = ss[FC + c];
        const ushort4 v = *(const ushort4*)(src + i);
        const float o0 = fmaf(b2f(v.x), sc, sh);
        const float o1 = fmaf(b2f(v.y), sc, sh);
        const float o2 = fmaf(b2f(v.z), sc, sh);
        const float o3 = fmaf(b2f(v.w), sc, sh);
        if (outf32) {
            float4 o; o.x = o0; o.y = o1; o.z = o2; o.w = o3;
            *(float4*)((float*)dst + i) = o;
        } else {
            ushort4 o;
            o.x = f2b(o0); o.y = f2b(o1); o.z = f2b(o2); o.w = f2b(o3);
            *(ushort4*)((u16*)dst + i) = o;
        }
    }
}

extern "C" void kernel_launch(void* const* d_in, const int* in_sizes, int n_in,
                              void* d_out, int out_size, void* d_ws, size_t ws_size,
                              hipStream_t stream)
{
    const size_t MiB = (size_t)1 << 20;
    const long sFH = (long)FC * HH;        // 1,048,576 elems (2 MiB bf16)
    const long sFF = (long)FC * FC;        // 1,048,576
    const long sFD = (long)FC * DD;        //   524,288 (1 MiB)
    const long PE  = (long)NB * FC * DD;   // 16,777,216 (32 MiB)

    const size_t GLDS = 49152;             // 48 KiB dynamic LDS -> 2 blocks/CU
    static bool s_attr = false;
    if (!s_attr) {
        s_attr = true;
        hipFuncSetAttribute(reinterpret_cast<const void*>(&gemm128x256_nt<true, false, true, false, false>),
                            hipFuncAttributeMaxDynamicSharedMemorySize, (int)GLDS);
        hipFuncSetAttribute(reinterpret_cast<const void*>(&gemm128x256_nt<false, true, false, false, false>),
                            hipFuncAttributeMaxDynamicSharedMemorySize, (int)GLDS);
        hipFuncSetAttribute(reinterpret_cast<const void*>(&gemm128x256_nt<false, false, false, false, false>),
                            hipFuncAttributeMaxDynamicSharedMemorySize, (int)GLDS);
        hipFuncSetAttribute(reinterpret_cast<const void*>(&gemm128x256_nt<true, false, true, false, true>),
                            hipFuncAttributeMaxDynamicSharedMemorySize, (int)GLDS);
        hipFuncSetAttribute(reinterpret_cast<const void*>(&gemm128x256_nt<true, false, true, true, false>),
                            hipFuncAttributeMaxDynamicSharedMemorySize, (int)GLDS);
    }

    // bf16 param packing offsets
    long off[16];
    long cur = 0;
    for (int i = 1; i < 15; ++i) { off[i] = cur; cur += ((long)in_sizes[i] + 7) & ~7L; }
    const size_t paramBytes = (size_t)cur * 2;

    // adaptive correlation chunk: scratch = cb*6 MiB (VT + W + V2)
    int cb = 32;
    while (cb > 1 &&
           64 * MiB + (size_t)cb * 6 * MiB + paramBytes + 131072 > ws_size)
        cb >>= 1;

    // ---- workspace layout ----
    u16* V   = (u16*)d_ws;                          // 64 MiB: v (N,F,H)
    u16* VT  = (u16*)((char*)d_ws + 64 * MiB);      // cb*2 MiB: v^T chunk
    u16* WW  = VT + (long)cb * sFH;                 // cb*2 MiB: w chunk
    u16* V2  = WW + (long)cb * sFF;                 // cb*2 MiB: v2 chunk
    u16* WC  = V2 + (long)cb * sFH;                 // packed bf16 params
    char* tail = (char*)(WC + cur);
    tail = (char*)(((uintptr_t)tail + 255) & ~(uintptr_t)255);
    float* SP0  = (float*)tail;                     // BN0 partials (2FC)
    float* SP1  = SP0 + 2 * FC;                     // v3 partials (3FC: S1,S2,Sxv)
    float* SPX  = SP1 + 3 * FC;                     // x partials (2FC)
    float* SP3  = SPX + 2 * FC;                     // BNo partials (2FC)
    float* SSF  = SP3 + 2 * FC;                     // generic folded (2FC)
    float* SSD  = SSF + 2 * FC;                     // BN1+BNf folded (4FC)
    int*   FLAG = (int*)(SSD + 4 * FC);
    // d_out (fp32 out => 64 MiB): lower 32 MiB = VX (v3->xr), upper = XB
    u16* VX  = (u16*)d_out;
    u16* XB  = (u16*)d_out + PE;                    // x as bf16
    u16* V4  = V;                                   // v4/t (N,F,D) reuses V
    u16* XRT = V + PE;                              // xr^T reuses V upper half

    const dim3 blk(256);
    const dim3 blk512(512);
    const dim3 egrid(4096);

    // 0. zero stats partials (SP0..SP3 = 9FC) + detect dtype; convert params+x
    init_detect<<<dim3(36), blk, 0, stream>>>(SP0, (const u32*)d_in[0], FLAG);
    ConvArgs ca;
    for (int i = 1; i < 15; ++i) {
        ca.src[i - 1] = d_in[i];
        ca.off[i - 1] = off[i];
        ca.n4[i - 1]  = (long)in_sizes[i] / 4;
    }
    convert_params<<<dim3(256), blk, 0, stream>>>(ca, WC, FLAG);
    convert_x_stats<<<dim3(1024), blk, 0, stream>>>(d_in[0], XB, PE / 4, FLAG, SPX);

    const u16* W0c = WC + off[1];
    const u16* b0c = WC + off[2];
    const u16* g0c = WC + off[3];
    const u16* be0c = WC + off[4];
    const u16* W1c = WC + off[5];
    const u16* b1c = WC + off[6];
    const u16* g1c = WC + off[7];
    const u16* be1c = WC + off[8];
    const u16* gfc = WC + off[9];
    const u16* bfc = WC + off[10];
    const u16* Wcc = WC + off[11];
    const u16* bcc = WC + off[12];
    const u16* goc = WC + off[13];
    const u16* boc = WC + off[14];

    // 1. v = x @ W0^T + b0  (BN0 stats fused into epilogue -> SP0)
    gemm128x256_nt<true, false, true, false, false><<<dim3(HH / 256, (NB * FC) / 128, 1), blk512, GLDS, stream>>>(
        XB, W0c, b0c, nullptr, V, SP0, NB * FC, HH, DD, DD, DD, HH, 0, 0, 0);
    fold_bn<<<dim3(4), blk, 0, stream>>>(SP0, g0c, be0c, SSF, 1.0f / (float)(NB * HH));

    // 2-5 per chunk: vT+BN0-apply (V in place + VT); w = softsign(v v^T);
    // v2 = w @ v (via vT); v3 = v2 @ W1^T + b1 (S1,S2,Sxv fused -> SP1)
    for (int bz0 = 0; bz0 < NB; bz0 += cb) {
        const int c = (NB - bz0 < cb) ? (NB - bz0) : cb;
        transpose_bn_bf16<<<dim3(HH / 32, FC / 32, c), blk, 0, stream>>>(
            V + bz0 * sFH, VT, V + bz0 * sFH, SSF, FC, HH, sFH, sFH);
        gemm128x256_nt<false, true, false, false, false><<<dim3(FC / 256, FC / 128, c), blk512, GLDS, stream>>>(
            V + bz0 * sFH, V + bz0 * sFH, nullptr, nullptr, WW, nullptr,
            FC, FC, HH, HH, HH, FC, sFH, sFH, sFF);
        gemm128x256_nt<false, false, false, false, false><<<dim3(HH / 256, FC / 128, c), blk512, GLDS, stream>>>(
            WW, VT, nullptr, nullptr, V2, nullptr,
            FC, HH, FC, FC, FC, HH, sFF, sFH, sFH);
        gemm128x256_nt<true, false, true, false, true><<<dim3(DD / 256, (c * FC) / 128, 1), blk512, GLDS, stream>>>(
            V2, W1c, b1c, XB + bz0 * sFD, VX + bz0 * sFD, SP1,
            c * FC, DD, HH, HH, HH, DD, 0, 0, 0);
    }

    // 6. fold BN1 + analytic BNf (s = BN1(v3)+x never materialized)
    fold2_bn<<<dim3(4), blk, 0, stream>>>(SP1, SPX, g1c, be1c, gfc, bfc,
                                          SSD, (float)(NB * DD));

    // 7. xr = BNf(BN1(v3)+x) fused into xr^T transpose (in-place VX + XRT)
    transpose_bn2_bf16<<<dim3(DD / 32, FC / 32, NB), blk, 0, stream>>>(
        VX, XB, XRT, VX, SSD, FC, DD, sFD, sFD);

    // 8. t = Wc @ xr + bc + xr (resid+bias+BNo-stats fused) -> V4
    gemm128x256_nt<true, false, true, true, false><<<dim3(DD / 256, FC / 128, NB), blk512, GLDS, stream>>>(
        Wcc, XRT, bcc, VX, V4, SP3, FC, DD, FC, FC, FC, DD, 0, sFD, sFD);
    fold_bn<<<dim3(4), blk, 0, stream>>>(SP3, goc, boc, SSF, 1.0f / (float)(NB * DD));

    // 9. out = BNo(t); out dtype per FLAG
    bn_apply<<<egrid, blk, 0, stream>>>(V4, SSF, d_out, FLAG, PE / 4, 9);
}